// Round 1
// baseline (888.727 us; speedup 1.0000x reference)
//
#include <hip/hip_runtime.h>
#include <math.h>

#define B 128
#define N 512
#define M 512
#define D 128

// ws layout (float offsets):
//   EK   [B][M][D] @ 0            (8388608 floats)
//   EKV  [B][M][D] @ 8388608
//   SQ/AAFM [B][N][D] @ 16777216  (sigmoid(q), overwritten in-place with aafm)
//   WkT [128][128] @ 25165824
//   WvT [128][128] @ 25182208
//   WqT [129][128] @ 25198592     (total ~100.9 MB)

__global__ void k_transpose(const float* __restrict__ in, float* __restrict__ out,
                            int R, int C) {
    int idx = blockIdx.x * 256 + threadIdx.x;
    if (idx < R * C) {
        int r = idx / C, c = idx % C;
        out[c * R + r] = in[idx];
    }
}

// EK/EKV: per block 16 m-rows. thread: (m_l = t>>4, eg = t&15) -> 8 e's for k and v.
__global__ __launch_bounds__(256) void k_kv(const float* __restrict__ enc,
        const float* __restrict__ WkT, const float* __restrict__ WvT,
        float* __restrict__ EK, float* __restrict__ EKV) {
    int b = blockIdx.y, m0 = blockIdx.x * 16;
    int t = threadIdx.x;
    int eg = t & 15, m_l = t >> 4, e0 = eg * 8;
    __shared__ __align__(16) float encL[16 * 132];
    const float4* ep = (const float4*)(enc + ((size_t)b * M + m0) * D);
#pragma unroll
    for (int i = 0; i < 2; i++) {
        int f = t + i * 256;           // 512 float4
        int r = f >> 5, c4 = f & 31;
        ((float4*)encL)[r * 33 + c4] = ep[f];
    }
    __syncthreads();
    float ka[8] = {0,0,0,0,0,0,0,0}, va[8] = {0,0,0,0,0,0,0,0};
    const float4* wk4 = (const float4*)WkT;
    const float4* wv4 = (const float4*)WvT;
#pragma unroll 4
    for (int d = 0; d < 128; d++) {
        float es = encL[m_l * 132 + d];
        float4 a0 = wk4[d * 32 + eg * 2], a1 = wk4[d * 32 + eg * 2 + 1];
        float4 b0 = wv4[d * 32 + eg * 2], b1 = wv4[d * 32 + eg * 2 + 1];
        ka[0] = fmaf(es, a0.x, ka[0]); ka[1] = fmaf(es, a0.y, ka[1]);
        ka[2] = fmaf(es, a0.z, ka[2]); ka[3] = fmaf(es, a0.w, ka[3]);
        ka[4] = fmaf(es, a1.x, ka[4]); ka[5] = fmaf(es, a1.y, ka[5]);
        ka[6] = fmaf(es, a1.z, ka[6]); ka[7] = fmaf(es, a1.w, ka[7]);
        va[0] = fmaf(es, b0.x, va[0]); va[1] = fmaf(es, b0.y, va[1]);
        va[2] = fmaf(es, b0.z, va[2]); va[3] = fmaf(es, b0.w, va[3]);
        va[4] = fmaf(es, b1.x, va[4]); va[5] = fmaf(es, b1.y, va[5]);
        va[6] = fmaf(es, b1.z, va[6]); va[7] = fmaf(es, b1.w, va[7]);
    }
    float ekv[8];
#pragma unroll
    for (int j = 0; j < 8; j++) ekv[j] = expf(ka[j]);
    float4 o0 = {ekv[0], ekv[1], ekv[2], ekv[3]};
    float4 o1 = {ekv[4], ekv[5], ekv[6], ekv[7]};
    float4 p0 = {ekv[0]*va[0], ekv[1]*va[1], ekv[2]*va[2], ekv[3]*va[3]};
    float4 p1 = {ekv[4]*va[4], ekv[5]*va[5], ekv[6]*va[6], ekv[7]*va[7]};
    size_t base = ((size_t)b * M + m0 + m_l) * D + e0;
    *(float4*)(EK + base)      = o0;
    *(float4*)(EK + base + 4)  = o1;
    *(float4*)(EKV + base)     = p0;
    *(float4*)(EKV + base + 4) = p1;
}

// q = [enc_last, load] @ WqT ; SQ = sigmoid(q)
__global__ __launch_bounds__(256) void k_q(const float* __restrict__ encl,
        const float* __restrict__ loadv, const float* __restrict__ WqT,
        float* __restrict__ SQ) {
    int b = blockIdx.y, n0 = blockIdx.x * 16;
    int t = threadIdx.x;
    int eg = t & 15, n_l = t >> 4, e0 = eg * 8;
    __shared__ __align__(16) float catL[16 * 132];
    const float4* ep = (const float4*)(encl + ((size_t)b * N + n0) * D);
#pragma unroll
    for (int i = 0; i < 2; i++) {
        int f = t + i * 256;
        int r = f >> 5, c4 = f & 31;
        ((float4*)catL)[r * 33 + c4] = ep[f];
    }
    if (t < 16) catL[t * 132 + 128] = loadv[(size_t)b * N + n0 + t];
    __syncthreads();
    float qa[8] = {0,0,0,0,0,0,0,0};
    const float4* wq4 = (const float4*)WqT;
    for (int c = 0; c < 129; c++) {
        float cs = catL[n_l * 132 + c];
        float4 a0 = wq4[c * 32 + eg * 2], a1 = wq4[c * 32 + eg * 2 + 1];
        qa[0] = fmaf(cs, a0.x, qa[0]); qa[1] = fmaf(cs, a0.y, qa[1]);
        qa[2] = fmaf(cs, a0.z, qa[2]); qa[3] = fmaf(cs, a0.w, qa[3]);
        qa[4] = fmaf(cs, a1.x, qa[4]); qa[5] = fmaf(cs, a1.y, qa[5]);
        qa[6] = fmaf(cs, a1.z, qa[6]); qa[7] = fmaf(cs, a1.w, qa[7]);
    }
    float s[8];
#pragma unroll
    for (int j = 0; j < 8; j++) s[j] = 1.0f / (1.0f + expf(-qa[j]));
    float4 o0 = {s[0], s[1], s[2], s[3]};
    float4 o1 = {s[4], s[5], s[6], s[7]};
    size_t base = ((size_t)b * N + n0 + n_l) * D + e0;
    *(float4*)(SQ + base)     = o0;
    *(float4*)(SQ + base + 4) = o1;
}

// num/den over m, then aafm = SQ * nan_to_num(num/den), in-place into SQ.
// block: 64 n-rows; threads 256 = 8 ng(8n) x 32 dg(4d). m-tile 32.
__global__ __launch_bounds__(256) void k_numden(const float* __restrict__ cd,
        const float* __restrict__ ninf, const float* __restrict__ EK,
        const float* __restrict__ EKV, float* __restrict__ SQ,
        const float* __restrict__ alpha1, const float* __restrict__ log_scale) {
    int b = blockIdx.y, n0 = blockIdx.x * 64;
    int t = threadIdx.x;
    int dg = t & 31, ng = t >> 5;
    __shared__ __align__(16) float ekL[32 * 128];
    __shared__ __align__(16) float ekvL[32 * 128];
    __shared__ __align__(16) float ebL[64 * 33];
    float a1ls = alpha1[0] * log_scale[0];
    float nacc[8][4], dacc[8][4];
#pragma unroll
    for (int i = 0; i < 8; i++)
#pragma unroll
        for (int j = 0; j < 4; j++) { nacc[i][j] = 0.f; dacc[i][j] = 0.f; }

    for (int mt = 0; mt < 16; mt++) {
        int m0 = mt * 32;
        __syncthreads();
        const float4* ek4  = (const float4*)(EK  + ((size_t)b * M + m0) * D);
        const float4* ekv4 = (const float4*)(EKV + ((size_t)b * M + m0) * D);
#pragma unroll
        for (int i = 0; i < 4; i++) {
            int f = t + i * 256;       // 1024 float4 = 32x128
            ((float4*)ekL)[f]  = ek4[f];
            ((float4*)ekvL)[f] = ekv4[f];
        }
#pragma unroll
        for (int i = 0; i < 8; i++) {
            int f = t + i * 256;       // 2048 = 64 rows x 32 cols
            int r = f >> 5, c = f & 31;
            size_t g = ((size_t)b * N + n0 + r) * M + m0 + c;
            float cdv = cd[g];
            float nv  = ninf[g];
            ebL[r * 33 + c] = expf(fmaf(-a1ls, cdv, nv));
        }
        __syncthreads();
#pragma unroll 2
        for (int m = 0; m < 32; m++) {
            float4 kv = ((const float4*)ekvL)[m * 32 + dg];
            float4 kk = ((const float4*)ekL)[m * 32 + dg];
#pragma unroll
            for (int i = 0; i < 8; i++) {
                float e = ebL[(ng * 8 + i) * 33 + m];
                nacc[i][0] = fmaf(e, kv.x, nacc[i][0]);
                nacc[i][1] = fmaf(e, kv.y, nacc[i][1]);
                nacc[i][2] = fmaf(e, kv.z, nacc[i][2]);
                nacc[i][3] = fmaf(e, kv.w, nacc[i][3]);
                dacc[i][0] = fmaf(e, kk.x, dacc[i][0]);
                dacc[i][1] = fmaf(e, kk.y, dacc[i][1]);
                dacc[i][2] = fmaf(e, kk.z, dacc[i][2]);
                dacc[i][3] = fmaf(e, kk.w, dacc[i][3]);
            }
        }
    }
#pragma unroll
    for (int i = 0; i < 8; i++) {
        size_t off = (((size_t)b * N + n0 + ng * 8 + i) * D + dg * 4) / 4;
        float4 sq = ((const float4*)SQ)[off];
        float4 w;
        w.x = dacc[i][0] != 0.f ? nacc[i][0] / dacc[i][0] : 0.f;
        w.y = dacc[i][1] != 0.f ? nacc[i][1] / dacc[i][1] : 0.f;
        w.z = dacc[i][2] != 0.f ? nacc[i][2] / dacc[i][2] : 0.f;
        w.w = dacc[i][3] != 0.f ? nacc[i][3] / dacc[i][3] : 0.f;
        float4 o = {sq.x * w.x, sq.y * w.y, sq.z * w.z, sq.w * w.w};
        ((float4*)SQ)[off] = o;
    }
}

// score = aafm @ enc^T ; logits = 10*tanh(score/sqrtD - a2*ls*cd) + ninf -> d_out
// block 128 thr: ng = t>>4 (8x8n=64 rows), mg = t&15; thread m = {mg*4..+3, 64+mg*4..+3}
__global__ __launch_bounds__(128) void k_score(const float* __restrict__ AAFM,
        const float* __restrict__ enc, const float* __restrict__ cd,
        const float* __restrict__ ninf, const float* __restrict__ alpha2,
        const float* __restrict__ log_scale, float* __restrict__ out) {
    int b = blockIdx.y, n0 = blockIdx.x * 64;
    int t = threadIdx.x;
    int mg = t & 15, ng = t >> 4;
    __shared__ __align__(16) float aafmL[64 * 133];
    __shared__ __align__(16) float encT[32 * 132];
    float a2ls = alpha2[0] * log_scale[0];
    const float invs = 0.08838834764831845f;  // 1/sqrt(128)

    const float4* a4 = (const float4*)(AAFM + ((size_t)b * N + n0) * D);
#pragma unroll
    for (int i = 0; i < 16; i++) {
        int f = t + i * 128;           // 2048 float4 = 64x128
        int r = f >> 5, c4 = f & 31;
        float4 v = a4[f];
        aafmL[r * 133 + c4 * 4 + 0] = v.x;
        aafmL[r * 133 + c4 * 4 + 1] = v.y;
        aafmL[r * 133 + c4 * 4 + 2] = v.z;
        aafmL[r * 133 + c4 * 4 + 3] = v.w;
    }

    for (int mt = 0; mt < 4; mt++) {
        int m0 = mt * 128;
        float sacc[8][8];
#pragma unroll
        for (int i = 0; i < 8; i++)
#pragma unroll
            for (int j = 0; j < 8; j++) sacc[i][j] = 0.f;

        for (int dt = 0; dt < 4; dt++) {
            __syncthreads();
            const float4* e4 = (const float4*)enc;
#pragma unroll
            for (int i = 0; i < 8; i++) {
                int f = t + i * 128;    // 1024 = 128 m x 8 c4
                int rm = f >> 3, c4 = f & 7;
                float4 v = e4[(((size_t)b * M + m0 + rm) * D + dt * 32) / 4 + c4];
                encT[(c4 * 4 + 0) * 132 + rm] = v.x;
                encT[(c4 * 4 + 1) * 132 + rm] = v.y;
                encT[(c4 * 4 + 2) * 132 + rm] = v.z;
                encT[(c4 * 4 + 3) * 132 + rm] = v.w;
            }
            __syncthreads();
#pragma unroll 2
            for (int dl = 0; dl < 32; dl++) {
                float4 e0 = ((const float4*)encT)[dl * 33 + mg];
                float4 e1 = ((const float4*)encT)[dl * 33 + 16 + mg];
#pragma unroll
                for (int i = 0; i < 8; i++) {
                    float a = aafmL[(ng * 8 + i) * 133 + dt * 32 + dl];
                    sacc[i][0] = fmaf(a, e0.x, sacc[i][0]);
                    sacc[i][1] = fmaf(a, e0.y, sacc[i][1]);
                    sacc[i][2] = fmaf(a, e0.z, sacc[i][2]);
                    sacc[i][3] = fmaf(a, e0.w, sacc[i][3]);
                    sacc[i][4] = fmaf(a, e1.x, sacc[i][4]);
                    sacc[i][5] = fmaf(a, e1.y, sacc[i][5]);
                    sacc[i][6] = fmaf(a, e1.z, sacc[i][6]);
                    sacc[i][7] = fmaf(a, e1.w, sacc[i][7]);
                }
            }
        }
#pragma unroll
        for (int i = 0; i < 8; i++) {
            size_t ro = ((size_t)b * N + n0 + ng * 8 + i) * M + m0;
            float4 c0 = *(const float4*)(cd + ro + mg * 4);
            float4 c1 = *(const float4*)(cd + ro + 64 + mg * 4);
            float4 f0 = *(const float4*)(ninf + ro + mg * 4);
            float4 f1 = *(const float4*)(ninf + ro + 64 + mg * 4);
            float4 o0, o1;
            o0.x = 10.f * tanhf(fmaf(sacc[i][0], invs, -a2ls * c0.x)) + f0.x;
            o0.y = 10.f * tanhf(fmaf(sacc[i][1], invs, -a2ls * c0.y)) + f0.y;
            o0.z = 10.f * tanhf(fmaf(sacc[i][2], invs, -a2ls * c0.z)) + f0.z;
            o0.w = 10.f * tanhf(fmaf(sacc[i][3], invs, -a2ls * c0.w)) + f0.w;
            o1.x = 10.f * tanhf(fmaf(sacc[i][4], invs, -a2ls * c1.x)) + f1.x;
            o1.y = 10.f * tanhf(fmaf(sacc[i][5], invs, -a2ls * c1.y)) + f1.y;
            o1.z = 10.f * tanhf(fmaf(sacc[i][6], invs, -a2ls * c1.z)) + f1.z;
            o1.w = 10.f * tanhf(fmaf(sacc[i][7], invs, -a2ls * c1.w)) + f1.w;
            *(float4*)(out + ro + mg * 4) = o0;
            *(float4*)(out + ro + 64 + mg * 4) = o1;
        }
    }
}

// in-place row softmax over M=512. block 256 = 4 rows x 64 lanes.
__global__ __launch_bounds__(256) void k_softmax(float* __restrict__ out) {
    int row = blockIdx.x * 4 + (threadIdx.x >> 6);
    int lane = threadIdx.x & 63;
    float4* p = (float4*)(out + (size_t)row * M);
    float4 v0 = p[lane * 2], v1 = p[lane * 2 + 1];
    float mx = fmaxf(fmaxf(fmaxf(v0.x, v0.y), fmaxf(v0.z, v0.w)),
                     fmaxf(fmaxf(v1.x, v1.y), fmaxf(v1.z, v1.w)));
#pragma unroll
    for (int s = 32; s > 0; s >>= 1) mx = fmaxf(mx, __shfl_xor(mx, s, 64));
    v0.x = expf(v0.x - mx); v0.y = expf(v0.y - mx);
    v0.z = expf(v0.z - mx); v0.w = expf(v0.w - mx);
    v1.x = expf(v1.x - mx); v1.y = expf(v1.y - mx);
    v1.z = expf(v1.z - mx); v1.w = expf(v1.w - mx);
    float sum = v0.x + v0.y + v0.z + v0.w + v1.x + v1.y + v1.z + v1.w;
#pragma unroll
    for (int s = 32; s > 0; s >>= 1) sum += __shfl_xor(sum, s, 64);
    float inv = 1.0f / sum;
    v0.x *= inv; v0.y *= inv; v0.z *= inv; v0.w *= inv;
    v1.x *= inv; v1.y *= inv; v1.z *= inv; v1.w *= inv;
    p[lane * 2] = v0; p[lane * 2 + 1] = v1;
}

extern "C" void kernel_launch(void* const* d_in, const int* in_sizes, int n_in,
                              void* d_out, int out_size, void* d_ws, size_t ws_size,
                              hipStream_t stream) {
    const float* encl  = (const float*)d_in[0];   // encoded_last_node (B,N,D)
    const float* loadv = (const float*)d_in[1];   // load (B,N)
    const float* cd    = (const float*)d_in[2];   // cur_dist (B,N,M)
    const float* ls    = (const float*)d_in[3];   // log_scale ()
    const float* ninf  = (const float*)d_in[4];   // ninf_mask (B,N,M)
    const float* enc   = (const float*)d_in[5];   // encoded_nodes (B,M,D)
    const float* Wq    = (const float*)d_in[6];   // (D, D+1)
    const float* Wk    = (const float*)d_in[7];   // (D, D)
    const float* Wv    = (const float*)d_in[8];   // (D, D)
    const float* a1    = (const float*)d_in[9];
    const float* a2    = (const float*)d_in[10];
    float* ws  = (float*)d_ws;
    float* EK  = ws;
    float* EKV = ws + 8388608;
    float* SQ  = ws + 16777216;
    float* WkT = ws + 25165824;
    float* WvT = WkT + 16384;
    float* WqT = WvT + 16384;
    float* out = (float*)d_out;

    k_transpose<<<64, 256, 0, stream>>>(Wk, WkT, 128, 128);
    k_transpose<<<64, 256, 0, stream>>>(Wv, WvT, 128, 128);
    k_transpose<<<65, 256, 0, stream>>>(Wq, WqT, 128, 129);
    k_kv<<<dim3(32, 128), 256, 0, stream>>>(enc, WkT, WvT, EK, EKV);
    k_q<<<dim3(32, 128), 256, 0, stream>>>(encl, loadv, WqT, SQ);
    k_numden<<<dim3(8, 128), 256, 0, stream>>>(cd, ninf, EK, EKV, SQ, a1, ls);
    k_score<<<dim3(8, 128), 128, 0, stream>>>(SQ, enc, cd, ninf, a2, ls, out);
    k_softmax<<<16384, 256, 0, stream>>>(out);
}

// Round 2
// 765.577 us; speedup vs baseline: 1.1609x; 1.1609x over previous
//
#include <hip/hip_runtime.h>
#include <math.h>

#define B 128
#define N 512
#define M 512
#define D 128

typedef __attribute__((ext_vector_type(8))) short s16x8;
typedef __attribute__((ext_vector_type(4))) short s16x4;
typedef __attribute__((ext_vector_type(4))) float f32x4;

#define MFMA16(a, b, c) __builtin_amdgcn_mfma_f32_16x16x32_bf16(a, b, c, 0, 0, 0)

// Truncation split: x ~= hi + lo, |x - hi - lo| <= ~2^-16 |x|
__device__ __forceinline__ void fsplit(float x, short& h, short& l) {
    unsigned u = __float_as_uint(x);
    h = (short)(u >> 16);
    float fh = __uint_as_float(u & 0xffff0000u);
    l = (short)(__float_as_uint(x - fh) >> 16);
}

__device__ __forceinline__ void fsplit8(float4 x0, float4 x1, s16x8& h, s16x8& l) {
    short a, b;
    fsplit(x0.x, a, b); h[0] = a; l[0] = b;
    fsplit(x0.y, a, b); h[1] = a; l[1] = b;
    fsplit(x0.z, a, b); h[2] = a; l[2] = b;
    fsplit(x0.w, a, b); h[3] = a; l[3] = b;
    fsplit(x1.x, a, b); h[4] = a; l[4] = b;
    fsplit(x1.y, a, b); h[5] = a; l[5] = b;
    fsplit(x1.z, a, b); h[6] = a; l[6] = b;
    fsplit(x1.w, a, b); h[7] = a; l[7] = b;
}

// Split Wk, Wv (128x128, row e, col d) and Wq's first 128 cols (row e, 129-stride)
__global__ void k_prep_w(const float* __restrict__ Wk, const float* __restrict__ Wv,
                         const float* __restrict__ Wq,
                         unsigned short* __restrict__ Wk_hi, unsigned short* __restrict__ Wk_lo,
                         unsigned short* __restrict__ Wv_hi, unsigned short* __restrict__ Wv_lo,
                         unsigned short* __restrict__ Wq_hi, unsigned short* __restrict__ Wq_lo) {
    int i = blockIdx.x * 256 + threadIdx.x;  // 0..49151
    short h, l;
    if (i < 16384) {
        fsplit(Wk[i], h, l); Wk_hi[i] = (unsigned short)h; Wk_lo[i] = (unsigned short)l;
    } else if (i < 32768) {
        int j = i - 16384;
        fsplit(Wv[j], h, l); Wv_hi[j] = (unsigned short)h; Wv_lo[j] = (unsigned short)l;
    } else {
        int j = i - 32768; int e = j >> 7, d = j & 127;
        fsplit(Wq[e * 129 + d], h, l); Wq_hi[j] = (unsigned short)h; Wq_lo[j] = (unsigned short)l;
    }
}

// k = enc@Wk^T, v = enc@Wv^T via MFMA; store EK^T, (EK*V)^T as bf16 hi/lo [b][e][m]
__global__ __launch_bounds__(256) void k_kv(const float* __restrict__ enc,
        const unsigned short* __restrict__ Wk_hi, const unsigned short* __restrict__ Wk_lo,
        const unsigned short* __restrict__ Wv_hi, const unsigned short* __restrict__ Wv_lo,
        unsigned short* __restrict__ EKT_hi, unsigned short* __restrict__ EKT_lo,
        unsigned short* __restrict__ EKVT_hi, unsigned short* __restrict__ EKVT_lo) {
    int b = blockIdx.y;
    int wave = threadIdx.x >> 6, lane = threadIdx.x & 63;
    int row = lane & 15, kg = lane >> 4;
    int m0 = blockIdx.x * 64 + wave * 16;
    f32x4 acc[16];
#pragma unroll
    for (int i = 0; i < 16; i++) acc[i] = (f32x4)0.f;
    const float* ap = enc + ((size_t)b * M + m0 + row) * D + kg * 8;
#pragma unroll
    for (int ks = 0; ks < 4; ks++) {
        float4 x0 = *(const float4*)(ap + ks * 32);
        float4 x1 = *(const float4*)(ap + ks * 32 + 4);
        s16x8 ah, al;
        fsplit8(x0, x1, ah, al);
        int wb = ks * 32 + kg * 8;
#pragma unroll
        for (int ct = 0; ct < 8; ct++) {
            int e = ct * 16 + row;
            s16x8 bh = *(const s16x8*)(Wk_hi + e * D + wb);
            s16x8 bl = *(const s16x8*)(Wk_lo + e * D + wb);
            acc[ct] = MFMA16(ah, bh, acc[ct]);
            acc[ct] = MFMA16(al, bh, acc[ct]);
            acc[ct] = MFMA16(ah, bl, acc[ct]);
            bh = *(const s16x8*)(Wv_hi + e * D + wb);
            bl = *(const s16x8*)(Wv_lo + e * D + wb);
            acc[8 + ct] = MFMA16(ah, bh, acc[8 + ct]);
            acc[8 + ct] = MFMA16(al, bh, acc[8 + ct]);
            acc[8 + ct] = MFMA16(ah, bl, acc[8 + ct]);
        }
    }
#pragma unroll
    for (int ct = 0; ct < 8; ct++) {
        int e = ct * 16 + row;
        s16x4 ekh, ekl, evh, evl;
#pragma unroll
        for (int r = 0; r < 4; r++) {
            float ek = expf(acc[ct][r]);
            float ev = ek * acc[8 + ct][r];
            short h, l;
            fsplit(ek, h, l); ekh[r] = h; ekl[r] = l;
            fsplit(ev, h, l); evh[r] = h; evl[r] = l;
        }
        size_t o = ((size_t)b * D + e) * M + m0 + kg * 4;
        *(s16x4*)(EKT_hi + o) = ekh;
        *(s16x4*)(EKT_lo + o) = ekl;
        *(s16x4*)(EKVT_hi + o) = evh;
        *(s16x4*)(EKVT_lo + o) = evl;
    }
}

// q = [encl, load]@Wq^T (K=128 MFMA + rank-1 col-128), SQ = sigmoid(q) f32 [b][n][e]
__global__ __launch_bounds__(256) void k_q(const float* __restrict__ encl,
        const float* __restrict__ loadv, const float* __restrict__ Wq,
        const unsigned short* __restrict__ Wq_hi, const unsigned short* __restrict__ Wq_lo,
        float* __restrict__ SQ) {
    int b = blockIdx.y;
    int wave = threadIdx.x >> 6, lane = threadIdx.x & 63;
    int row = lane & 15, kg = lane >> 4;
    int n0 = blockIdx.x * 64 + wave * 16;
    f32x4 acc[8];
#pragma unroll
    for (int i = 0; i < 8; i++) acc[i] = (f32x4)0.f;
    const float* ap = encl + ((size_t)b * N + n0 + row) * D + kg * 8;
#pragma unroll
    for (int ks = 0; ks < 4; ks++) {
        float4 x0 = *(const float4*)(ap + ks * 32);
        float4 x1 = *(const float4*)(ap + ks * 32 + 4);
        s16x8 ah, al;
        fsplit8(x0, x1, ah, al);
        int wb = ks * 32 + kg * 8;
#pragma unroll
        for (int ct = 0; ct < 8; ct++) {
            int e = ct * 16 + row;
            s16x8 bh = *(const s16x8*)(Wq_hi + e * D + wb);
            s16x8 bl = *(const s16x8*)(Wq_lo + e * D + wb);
            acc[ct] = MFMA16(ah, bh, acc[ct]);
            acc[ct] = MFMA16(al, bh, acc[ct]);
            acc[ct] = MFMA16(ah, bl, acc[ct]);
        }
    }
#pragma unroll
    for (int r = 0; r < 4; r++) {
        int n = n0 + kg * 4 + r;
        float lv = loadv[(size_t)b * N + n];
        size_t ro = ((size_t)b * N + n) * D;
#pragma unroll
        for (int ct = 0; ct < 8; ct++) {
            int e = ct * 16 + row;
            float q = acc[ct][r] + lv * Wq[e * 129 + 128];
            SQ[ro + e] = 1.f / (1.f + expf(-q));
        }
    }
}

// num=EB@EKV, den=EB@EK (EB=exp(-a1*ls*cd+ninf) on the fly);
// aafm = SQ*nan_to_num(num/den); packed bf16 hi|lo<<16 written IN PLACE over SQ.
__global__ __launch_bounds__(256) void k_numden(const float* __restrict__ cd,
        const float* __restrict__ ninf,
        const unsigned short* __restrict__ EKT_hi, const unsigned short* __restrict__ EKT_lo,
        const unsigned short* __restrict__ EKVT_hi, const unsigned short* __restrict__ EKVT_lo,
        float* __restrict__ SQ,
        const float* __restrict__ a1p, const float* __restrict__ lsp) {
    int b = blockIdx.y;
    int wave = threadIdx.x >> 6, lane = threadIdx.x & 63;
    int row = lane & 15, kg = lane >> 4;
    int n0 = blockIdx.x * 64 + wave * 16;
    float a1ls = a1p[0] * lsp[0];
    f32x4 acc[16];
#pragma unroll
    for (int i = 0; i < 16; i++) acc[i] = (f32x4)0.f;
    const float* cdp = cd + ((size_t)b * N + n0 + row) * M + kg * 8;
    const float* nfp = ninf + ((size_t)b * N + n0 + row) * M + kg * 8;
    for (int mt = 0; mt < 16; mt++) {
        int m = mt * 32;
        float4 c0 = *(const float4*)(cdp + m);
        float4 c1 = *(const float4*)(cdp + m + 4);
        float4 f0 = *(const float4*)(nfp + m);
        float4 f1 = *(const float4*)(nfp + m + 4);
        float4 e0, e1;
        e0.x = expf(fmaf(-a1ls, c0.x, f0.x));
        e0.y = expf(fmaf(-a1ls, c0.y, f0.y));
        e0.z = expf(fmaf(-a1ls, c0.z, f0.z));
        e0.w = expf(fmaf(-a1ls, c0.w, f0.w));
        e1.x = expf(fmaf(-a1ls, c1.x, f1.x));
        e1.y = expf(fmaf(-a1ls, c1.y, f1.y));
        e1.z = expf(fmaf(-a1ls, c1.z, f1.z));
        e1.w = expf(fmaf(-a1ls, c1.w, f1.w));
        s16x8 ah, al;
        fsplit8(e0, e1, ah, al);
        size_t bb = (size_t)b * D * M + m + kg * 8;
#pragma unroll
        for (int ct = 0; ct < 8; ct++) {
            size_t o = bb + (size_t)(ct * 16 + row) * M;
            s16x8 bh = *(const s16x8*)(EKVT_hi + o);
            s16x8 bl = *(const s16x8*)(EKVT_lo + o);
            acc[ct] = MFMA16(ah, bh, acc[ct]);
            acc[ct] = MFMA16(al, bh, acc[ct]);
            acc[ct] = MFMA16(ah, bl, acc[ct]);
            bh = *(const s16x8*)(EKT_hi + o);
            bl = *(const s16x8*)(EKT_lo + o);
            acc[8 + ct] = MFMA16(ah, bh, acc[8 + ct]);
            acc[8 + ct] = MFMA16(al, bh, acc[8 + ct]);
            acc[8 + ct] = MFMA16(ah, bl, acc[8 + ct]);
        }
    }
#pragma unroll
    for (int r = 0; r < 4; r++) {
        int n = n0 + kg * 4 + r;
        size_t ro = ((size_t)b * N + n) * D;
#pragma unroll
        for (int ct = 0; ct < 8; ct++) {
            int e = ct * 16 + row;
            float num = acc[ct][r], den = acc[8 + ct][r];
            float w = (den != 0.f) ? num / den : 0.f;
            float aafm = SQ[ro + e] * w;
            unsigned u = __float_as_uint(aafm);
            unsigned hi = u >> 16;
            float fh = __uint_as_float(u & 0xffff0000u);
            unsigned lo = __float_as_uint(aafm - fh) >> 16;
            SQ[ro + e] = __uint_as_float(hi | (lo << 16));   // same-type store: no TBAA hazard
        }
    }
}

// Split enc into bf16 hi/lo [b][m][e] (into the dead EKT region)
__global__ void k_encsplit(const float* __restrict__ enc,
                           unsigned short* __restrict__ Eh, unsigned short* __restrict__ El) {
    size_t i = ((size_t)blockIdx.x * 256 + threadIdx.x) * 4;
    float4 x = *(const float4*)(enc + i);
    s16x4 h, l; short a, b;
    fsplit(x.x, a, b); h[0] = a; l[0] = b;
    fsplit(x.y, a, b); h[1] = a; l[1] = b;
    fsplit(x.z, a, b); h[2] = a; l[2] = b;
    fsplit(x.w, a, b); h[3] = a; l[3] = b;
    *(s16x4*)(Eh + i) = h;
    *(s16x4*)(El + i) = l;
}

// score = AAFM@enc^T; logits = 10*tanh(score/sqrtD - a2*ls*cd)+ninf; fused row softmax.
// 8 waves: (w>>1) picks 16-row group, (w&1) picks 256-col half.
__global__ __launch_bounds__(512) void k_score(const float* __restrict__ AAFM,
        const unsigned short* __restrict__ Eh, const unsigned short* __restrict__ El,
        const float* __restrict__ cd, const float* __restrict__ ninf,
        const float* __restrict__ a2p, const float* __restrict__ lsp,
        float* __restrict__ out) {
    int b = blockIdx.y;
    int w = threadIdx.x >> 6, lane = threadIdx.x & 63;
    int row = lane & 15, kg = lane >> 4;
    int nr0 = blockIdx.x * 64 + (w >> 1) * 16;
    int mc0 = (w & 1) * 256;
    float a2ls = a2p[0] * lsp[0];
    const float invs = 0.08838834764831845f;  // 1/sqrt(128)
    f32x4 acc[16];
#pragma unroll
    for (int i = 0; i < 16; i++) acc[i] = (f32x4)0.f;
    const float* apk = AAFM + ((size_t)b * N + nr0 + row) * D + kg * 8;
#pragma unroll
    for (int es = 0; es < 4; es++) {
        float4 w0 = *(const float4*)(apk + es * 32);
        float4 w1 = *(const float4*)(apk + es * 32 + 4);
        s16x8 ah, al;
        unsigned u;
        u = __float_as_uint(w0.x); ah[0] = (short)(u & 0xffff); al[0] = (short)(u >> 16);
        u = __float_as_uint(w0.y); ah[1] = (short)(u & 0xffff); al[1] = (short)(u >> 16);
        u = __float_as_uint(w0.z); ah[2] = (short)(u & 0xffff); al[2] = (short)(u >> 16);
        u = __float_as_uint(w0.w); ah[3] = (short)(u & 0xffff); al[3] = (short)(u >> 16);
        u = __float_as_uint(w1.x); ah[4] = (short)(u & 0xffff); al[4] = (short)(u >> 16);
        u = __float_as_uint(w1.y); ah[5] = (short)(u & 0xffff); al[5] = (short)(u >> 16);
        u = __float_as_uint(w1.z); ah[6] = (short)(u & 0xffff); al[6] = (short)(u >> 16);
        u = __float_as_uint(w1.w); ah[7] = (short)(u & 0xffff); al[7] = (short)(u >> 16);
        int eo = es * 32 + kg * 8;
#pragma unroll
        for (int ct = 0; ct < 16; ct++) {
            size_t o = ((size_t)b * M + mc0 + ct * 16 + row) * D + eo;
            s16x8 bh = *(const s16x8*)(Eh + o);
            s16x8 bl = *(const s16x8*)(El + o);
            acc[ct] = MFMA16(ah, bh, acc[ct]);
            acc[ct] = MFMA16(al, bh, acc[ct]);
            acc[ct] = MFMA16(ah, bl, acc[ct]);
        }
    }
    __shared__ float redm[64][2];
    __shared__ float reds[64][2];
#pragma unroll
    for (int r = 0; r < 4; r++) {
        int n = nr0 + kg * 4 + r;
        size_t ro = ((size_t)b * N + n) * M + mc0 + row;
#pragma unroll
        for (int ct = 0; ct < 16; ct++) {
            float c = cd[ro + ct * 16];
            float f = ninf[ro + ct * 16];
            acc[ct][r] = 10.f * tanhf(fmaf(acc[ct][r], invs, -a2ls * c)) + f;
        }
    }
    float mx[4], sm[4];
#pragma unroll
    for (int r = 0; r < 4; r++) {
        float m = acc[0][r];
#pragma unroll
        for (int ct = 1; ct < 16; ct++) m = fmaxf(m, acc[ct][r]);
#pragma unroll
        for (int s = 1; s < 16; s <<= 1) m = fmaxf(m, __shfl_xor(m, s, 64));
        mx[r] = m;
    }
    int rl = (w >> 1) * 16 + kg * 4;
    if (row == 0) {
#pragma unroll
        for (int r = 0; r < 4; r++) redm[rl + r][w & 1] = mx[r];
    }
    __syncthreads();
#pragma unroll
    for (int r = 0; r < 4; r++) {
        float m = fmaxf(redm[rl + r][0], redm[rl + r][1]);
        float s = 0.f;
#pragma unroll
        for (int ct = 0; ct < 16; ct++) {
            float e = expf(acc[ct][r] - m);
            acc[ct][r] = e;
            s += e;
        }
#pragma unroll
        for (int sh = 1; sh < 16; sh <<= 1) s += __shfl_xor(s, sh, 64);
        sm[r] = s;
    }
    if (row == 0) {
#pragma unroll
        for (int r = 0; r < 4; r++) reds[rl + r][w & 1] = sm[r];
    }
    __syncthreads();
#pragma unroll
    for (int r = 0; r < 4; r++) {
        float inv = 1.f / (reds[rl + r][0] + reds[rl + r][1]);
        size_t ro = ((size_t)b * N + nr0 + kg * 4 + r) * M + mc0 + row;
#pragma unroll
        for (int ct = 0; ct < 16; ct++) {
            out[ro + ct * 16] = acc[ct][r] * inv;
        }
    }
}

extern "C" void kernel_launch(void* const* d_in, const int* in_sizes, int n_in,
                              void* d_out, int out_size, void* d_ws, size_t ws_size,
                              hipStream_t stream) {
    const float* encl  = (const float*)d_in[0];
    const float* loadv = (const float*)d_in[1];
    const float* cdist = (const float*)d_in[2];
    const float* ls    = (const float*)d_in[3];
    const float* ninf  = (const float*)d_in[4];
    const float* enc   = (const float*)d_in[5];
    const float* Wq    = (const float*)d_in[6];
    const float* Wk    = (const float*)d_in[7];
    const float* Wv    = (const float*)d_in[8];
    const float* a1    = (const float*)d_in[9];
    const float* a2    = (const float*)d_in[10];
    char* ws = (char*)d_ws;
    unsigned short* EKT_hi  = (unsigned short*)(ws);
    unsigned short* EKT_lo  = (unsigned short*)(ws + 16777216);
    unsigned short* EKVT_hi = (unsigned short*)(ws + 33554432);
    unsigned short* EKVT_lo = (unsigned short*)(ws + 50331648);
    float*          SQ      = (float*)(ws + 67108864);
    unsigned short* Wk_hi   = (unsigned short*)(ws + 100663296);
    unsigned short* Wk_lo   = (unsigned short*)(ws + 100663296 + 32768);
    unsigned short* Wv_hi   = (unsigned short*)(ws + 100663296 + 65536);
    unsigned short* Wv_lo   = (unsigned short*)(ws + 100663296 + 98304);
    unsigned short* Wq_hi   = (unsigned short*)(ws + 100663296 + 131072);
    unsigned short* Wq_lo   = (unsigned short*)(ws + 100663296 + 163840);
    // ENC split reuses the dead EKT region after k_numden
    unsigned short* ENC_hi  = EKT_hi;
    unsigned short* ENC_lo  = EKT_lo;
    float* out = (float*)d_out;

    k_prep_w<<<192, 256, 0, stream>>>(Wk, Wv, Wq, Wk_hi, Wk_lo, Wv_hi, Wv_lo, Wq_hi, Wq_lo);
    k_kv<<<dim3(8, 128), 256, 0, stream>>>(enc, Wk_hi, Wk_lo, Wv_hi, Wv_lo,
                                           EKT_hi, EKT_lo, EKVT_hi, EKVT_lo);
    k_q<<<dim3(8, 128), 256, 0, stream>>>(encl, loadv, Wq, Wq_hi, Wq_lo, SQ);
    k_numden<<<dim3(8, 128), 256, 0, stream>>>(cdist, ninf, EKT_hi, EKT_lo,
                                               EKVT_hi, EKVT_lo, SQ, a1, ls);
    k_encsplit<<<8192, 256, 0, stream>>>(enc, ENC_hi, ENC_lo);
    k_score<<<dim3(8, 128), 512, 0, stream>>>(SQ, ENC_hi, ENC_lo, cdist, ninf, a2, ls, out);
}

// Round 3
// 589.705 us; speedup vs baseline: 1.5071x; 1.2982x over previous
//
#include <hip/hip_runtime.h>
#include <math.h>

#define B 128
#define N 512
#define M 512
#define D 128

typedef __attribute__((ext_vector_type(8))) short s16x8;
typedef __attribute__((ext_vector_type(4))) short s16x4;
typedef __attribute__((ext_vector_type(4))) float f32x4;

#define MFMA16(a, b, c) __builtin_amdgcn_mfma_f32_16x16x32_bf16(a, b, c, 0, 0, 0)

__device__ __forceinline__ void gload16(const void* g, void* l) {
    __builtin_amdgcn_global_load_lds(
        (const __attribute__((address_space(1))) unsigned int*)g,
        (__attribute__((address_space(3))) unsigned int*)l, 16, 0, 0);
}

// Truncation split: x ~= hi + lo
__device__ __forceinline__ void fsplit(float x, short& h, short& l) {
    unsigned u = __float_as_uint(x);
    h = (short)(u >> 16);
    float fh = __uint_as_float(u & 0xffff0000u);
    l = (short)(__float_as_uint(x - fh) >> 16);
}

__device__ __forceinline__ void fsplit8(float4 x0, float4 x1, s16x8& h, s16x8& l) {
    short a, b;
    fsplit(x0.x, a, b); h[0] = a; l[0] = b;
    fsplit(x0.y, a, b); h[1] = a; l[1] = b;
    fsplit(x0.z, a, b); h[2] = a; l[2] = b;
    fsplit(x0.w, a, b); h[3] = a; l[3] = b;
    fsplit(x1.x, a, b); h[4] = a; l[4] = b;
    fsplit(x1.y, a, b); h[5] = a; l[5] = b;
    fsplit(x1.z, a, b); h[6] = a; l[6] = b;
    fsplit(x1.w, a, b); h[7] = a; l[7] = b;
}

__global__ void k_prep_w(const float* __restrict__ Wk, const float* __restrict__ Wv,
                         const float* __restrict__ Wq,
                         unsigned short* __restrict__ Wk_hi, unsigned short* __restrict__ Wk_lo,
                         unsigned short* __restrict__ Wv_hi, unsigned short* __restrict__ Wv_lo,
                         unsigned short* __restrict__ Wq_hi, unsigned short* __restrict__ Wq_lo) {
    int i = blockIdx.x * 256 + threadIdx.x;  // 0..49151
    short h, l;
    if (i < 16384) {
        fsplit(Wk[i], h, l); Wk_hi[i] = (unsigned short)h; Wk_lo[i] = (unsigned short)l;
    } else if (i < 32768) {
        int j = i - 16384;
        fsplit(Wv[j], h, l); Wv_hi[j] = (unsigned short)h; Wv_lo[j] = (unsigned short)l;
    } else {
        int j = i - 32768; int e = j >> 7, d = j & 127;
        fsplit(Wq[e * 129 + d], h, l); Wq_hi[j] = (unsigned short)h; Wq_lo[j] = (unsigned short)l;
    }
}

// k = enc@Wk^T, v = enc@Wv^T; store EK^T/(EK*V)^T bf16 hi/lo [b][e][m],
// SWIZZLED: within each 32-m group, 8-m chunk c stored at c ^ (e&3).
__global__ __launch_bounds__(256) void k_kv(const float* __restrict__ enc,
        const unsigned short* __restrict__ Wk_hi, const unsigned short* __restrict__ Wk_lo,
        const unsigned short* __restrict__ Wv_hi, const unsigned short* __restrict__ Wv_lo,
        unsigned short* __restrict__ EKT_hi, unsigned short* __restrict__ EKT_lo,
        unsigned short* __restrict__ EKVT_hi, unsigned short* __restrict__ EKVT_lo) {
    int b = blockIdx.y;
    int wave = threadIdx.x >> 6, lane = threadIdx.x & 63;
    int row = lane & 15, kg = lane >> 4;
    int m0 = blockIdx.x * 64 + wave * 16;
    f32x4 acc[16];
#pragma unroll
    for (int i = 0; i < 16; i++) acc[i] = (f32x4)0.f;
    const float* ap = enc + ((size_t)b * M + m0 + row) * D + kg * 8;
#pragma unroll
    for (int ks = 0; ks < 4; ks++) {
        float4 x0 = *(const float4*)(ap + ks * 32);
        float4 x1 = *(const float4*)(ap + ks * 32 + 4);
        s16x8 ah, al;
        fsplit8(x0, x1, ah, al);
        int wb = ks * 32 + kg * 8;
#pragma unroll
        for (int ct = 0; ct < 8; ct++) {
            int e = ct * 16 + row;
            s16x8 bh = *(const s16x8*)(Wk_hi + e * D + wb);
            s16x8 bl = *(const s16x8*)(Wk_lo + e * D + wb);
            acc[ct] = MFMA16(ah, bh, acc[ct]);
            acc[ct] = MFMA16(al, bh, acc[ct]);
            acc[ct] = MFMA16(ah, bl, acc[ct]);
            bh = *(const s16x8*)(Wv_hi + e * D + wb);
            bl = *(const s16x8*)(Wv_lo + e * D + wb);
            acc[8 + ct] = MFMA16(ah, bh, acc[8 + ct]);
            acc[8 + ct] = MFMA16(al, bh, acc[8 + ct]);
            acc[8 + ct] = MFMA16(ah, bl, acc[8 + ct]);
        }
    }
#pragma unroll
    for (int ct = 0; ct < 8; ct++) {
        int e = ct * 16 + row;
        s16x4 ekh, ekl, evh, evl;
#pragma unroll
        for (int r = 0; r < 4; r++) {
            float ek = expf(acc[ct][r]);
            float ev = ek * acc[8 + ct][r];
            short h, l;
            fsplit(ek, h, l); ekh[r] = h; ekl[r] = l;
            fsplit(ev, h, l); evh[r] = h; evl[r] = l;
        }
        int m = m0 + kg * 4;
        int chunk = (m & 31) >> 3;
        int p = chunk ^ (e & 3);
        size_t o = ((size_t)b * D + e) * M + (size_t)(m & ~31) + p * 8 + (m & 7);
        *(s16x4*)(EKT_hi + o) = ekh;
        *(s16x4*)(EKT_lo + o) = ekl;
        *(s16x4*)(EKVT_hi + o) = evh;
        *(s16x4*)(EKVT_lo + o) = evl;
    }
}

// q = [encl, load]@Wq^T; SQ = sigmoid(q) f32 [b][n][e]
__global__ __launch_bounds__(256) void k_q(const float* __restrict__ encl,
        const float* __restrict__ loadv, const float* __restrict__ Wq,
        const unsigned short* __restrict__ Wq_hi, const unsigned short* __restrict__ Wq_lo,
        float* __restrict__ SQ) {
    int b = blockIdx.y;
    int wave = threadIdx.x >> 6, lane = threadIdx.x & 63;
    int row = lane & 15, kg = lane >> 4;
    int n0 = blockIdx.x * 64 + wave * 16;
    f32x4 acc[8];
#pragma unroll
    for (int i = 0; i < 8; i++) acc[i] = (f32x4)0.f;
    const float* ap = encl + ((size_t)b * N + n0 + row) * D + kg * 8;
#pragma unroll
    for (int ks = 0; ks < 4; ks++) {
        float4 x0 = *(const float4*)(ap + ks * 32);
        float4 x1 = *(const float4*)(ap + ks * 32 + 4);
        s16x8 ah, al;
        fsplit8(x0, x1, ah, al);
        int wb = ks * 32 + kg * 8;
#pragma unroll
        for (int ct = 0; ct < 8; ct++) {
            int e = ct * 16 + row;
            s16x8 bh = *(const s16x8*)(Wq_hi + e * D + wb);
            s16x8 bl = *(const s16x8*)(Wq_lo + e * D + wb);
            acc[ct] = MFMA16(ah, bh, acc[ct]);
            acc[ct] = MFMA16(al, bh, acc[ct]);
            acc[ct] = MFMA16(ah, bl, acc[ct]);
        }
    }
#pragma unroll
    for (int r = 0; r < 4; r++) {
        int n = n0 + kg * 4 + r;
        float lv = loadv[(size_t)b * N + n];
        size_t ro = ((size_t)b * N + n) * D;
#pragma unroll
        for (int ct = 0; ct < 8; ct++) {
            int e = ct * 16 + row;
            float q = acc[ct][r] + lv * Wq[e * 129 + 128];
            SQ[ro + e] = 1.f / (1.f + expf(-q));
        }
    }
}

// num=EB@EKV, den=EB@EK with LDS-staged B tiles (global_load_lds, swizzled layout).
// Grid 1024 flat, XCD-bijective: same-b blocks co-resident per XCD.
__global__ __launch_bounds__(256) void k_numden(
        const float* __restrict__ cd, const float* __restrict__ ninf,
        const unsigned short* __restrict__ EKVT_hi, const unsigned short* __restrict__ EKVT_lo,
        const unsigned short* __restrict__ EKT_hi, const unsigned short* __restrict__ EKT_lo,
        float* __restrict__ SQ,
        const float* __restrict__ a1p, const float* __restrict__ lsp) {
    int o = blockIdx.x;
    int jj = o >> 3;
    int b = (o & 7) + ((jj >> 3) << 3);   // 16 b's per XCD
    int nb = jj & 7;
    int w = threadIdx.x >> 6, lane = threadIdx.x & 63;
    int row = lane & 15, kg = lane >> 4;
    int n0 = nb * 64 + w * 16;
    __shared__ __align__(16) char lds[32768];  // [4 arrays][128 e][64 B]
    float a1ls = a1p[0] * lsp[0];
    const char* gbase = (const char*)(w == 0 ? EKVT_hi : w == 1 ? EKVT_lo
                                    : w == 2 ? EKT_hi : EKT_lo)
                        + (size_t)b * D * M * 2;
    char* ldst = lds + w * 8192 + lane * 16;
    int srow = lane >> 2, schunk = lane & 3;
    f32x4 acc[16];
#pragma unroll
    for (int i = 0; i < 16; i++) acc[i] = (f32x4)0.f;
    const float* cdp = cd + ((size_t)b * N + n0 + row) * M + kg * 8;
    const float* nfp = ninf + ((size_t)b * N + n0 + row) * M + kg * 8;
    int rb = row * 64 + ((kg ^ (row & 3)) << 4);

    for (int mt = 0; mt < 16; mt++) {
        __syncthreads();
        // wave w stages array w: 8 KB = 8 x (64 lanes x 16 B), linear copy
#pragma unroll
        for (int jv = 0; jv < 8; jv++) {
            gload16(gbase + (size_t)(jv * 16 + srow) * 1024 + mt * 64 + schunk * 16,
                    ldst + jv * 1024);
        }
        // A operand: EB = exp(-a1*ls*cd + ninf), split to bf16 hi/lo
        int m = mt * 32;
        float4 c0 = *(const float4*)(cdp + m);
        float4 c1 = *(const float4*)(cdp + m + 4);
        float4 f0 = *(const float4*)(nfp + m);
        float4 f1 = *(const float4*)(nfp + m + 4);
        float4 e0, e1;
        e0.x = expf(fmaf(-a1ls, c0.x, f0.x));
        e0.y = expf(fmaf(-a1ls, c0.y, f0.y));
        e0.z = expf(fmaf(-a1ls, c0.z, f0.z));
        e0.w = expf(fmaf(-a1ls, c0.w, f0.w));
        e1.x = expf(fmaf(-a1ls, c1.x, f1.x));
        e1.y = expf(fmaf(-a1ls, c1.y, f1.y));
        e1.z = expf(fmaf(-a1ls, c1.z, f1.z));
        e1.w = expf(fmaf(-a1ls, c1.w, f1.w));
        s16x8 ah, al;
        fsplit8(e0, e1, ah, al);
        __syncthreads();   // drains vmcnt(0): LDS tiles + nothing else pending
#pragma unroll
        for (int ct = 0; ct < 8; ct++) {
            int ro = ct * 1024 + rb;
            s16x8 bh = *(const s16x8*)(lds + ro);             // EKVT_hi
            s16x8 bl = *(const s16x8*)(lds + 8192 + ro);      // EKVT_lo
            acc[ct] = MFMA16(ah, bh, acc[ct]);
            acc[ct] = MFMA16(al, bh, acc[ct]);
            acc[ct] = MFMA16(ah, bl, acc[ct]);
            bh = *(const s16x8*)(lds + 16384 + ro);           // EKT_hi
            bl = *(const s16x8*)(lds + 24576 + ro);           // EKT_lo
            acc[8 + ct] = MFMA16(ah, bh, acc[8 + ct]);
            acc[8 + ct] = MFMA16(al, bh, acc[8 + ct]);
            acc[8 + ct] = MFMA16(ah, bl, acc[8 + ct]);
        }
    }
#pragma unroll
    for (int r = 0; r < 4; r++) {
        int n = n0 + kg * 4 + r;
        size_t ro = ((size_t)b * N + n) * D;
#pragma unroll
        for (int ct = 0; ct < 8; ct++) {
            int e = ct * 16 + row;
            float num = acc[ct][r], den = acc[8 + ct][r];
            float ww = (den != 0.f) ? num / den : 0.f;
            float aafm = SQ[ro + e] * ww;
            unsigned u = __float_as_uint(aafm);
            unsigned hi = u >> 16;
            float fh = __uint_as_float(u & 0xffff0000u);
            unsigned lo = __float_as_uint(aafm - fh) >> 16;
            SQ[ro + e] = __uint_as_float(hi | (lo << 16));
        }
    }
}

// Split enc -> bf16 hi/lo [b][m][128e], SWIZZLED: 8-e chunk c at c ^ (m&7)
__global__ void k_encsplit(const float* __restrict__ enc,
                           unsigned short* __restrict__ Eh, unsigned short* __restrict__ El) {
    size_t i = (size_t)blockIdx.x * 256 + threadIdx.x;   // chunk id, 1,048,576 total
    size_t bm = i >> 4;
    int c = (int)(i & 15);
    int m = (int)(bm & 511);
    int p = c ^ (m & 7);
    const float* src = enc + bm * 128 + c * 8;
    float4 x0 = *(const float4*)(src);
    float4 x1 = *(const float4*)(src + 4);
    s16x8 h, l;
    fsplit8(x0, x1, h, l);
    *(s16x8*)(Eh + bm * 128 + p * 8) = h;
    *(s16x8*)(El + bm * 128 + p * 8) = l;
}

// score = AAFM@enc^T (LDS-staged enc), logits = 10*tanh(s/sqrtD - a2*ls*cd)+ninf,
// fused row softmax. Grid 2048 flat XCD-bijective; block 256 = 4 waves (ng x mh).
__global__ __launch_bounds__(256) void k_score(
        const float* __restrict__ AAFM,
        const unsigned short* __restrict__ Eh, const unsigned short* __restrict__ El,
        const float* __restrict__ cd, const float* __restrict__ ninf,
        const float* __restrict__ a2p, const float* __restrict__ lsp,
        float* __restrict__ out) {
    int o = blockIdx.x;
    int j = o >> 3;
    int b = (o & 7) + ((j >> 4) << 3);
    int nb = j & 15;
    int n0 = nb * 32;
    int w = threadIdx.x >> 6, lane = threadIdx.x & 63;
    int row = lane & 15, kg = lane >> 4;
    int ng = w >> 1, mh = w & 1;
    __shared__ __align__(16) char lds[32768];  // [hi|lo][64 m][256 B]
    float a2ls = a2p[0] * lsp[0];
    const float invs = 0.08838834764831845f;

    // A preload: 16 rows of packed AAFM, this lane's k-slices
    const float* apk = AAFM + ((size_t)b * N + n0 + ng * 16 + row) * D + kg * 8;
    s16x8 ah[4], al[4];
#pragma unroll
    for (int es = 0; es < 4; es++) {
        float4 w0 = *(const float4*)(apk + es * 32);
        float4 w1 = *(const float4*)(apk + es * 32 + 4);
        unsigned u;
        u = __float_as_uint(w0.x); ah[es][0] = (short)(u & 0xffff); al[es][0] = (short)(u >> 16);
        u = __float_as_uint(w0.y); ah[es][1] = (short)(u & 0xffff); al[es][1] = (short)(u >> 16);
        u = __float_as_uint(w0.z); ah[es][2] = (short)(u & 0xffff); al[es][2] = (short)(u >> 16);
        u = __float_as_uint(w0.w); ah[es][3] = (short)(u & 0xffff); al[es][3] = (short)(u >> 16);
        u = __float_as_uint(w1.x); ah[es][4] = (short)(u & 0xffff); al[es][4] = (short)(u >> 16);
        u = __float_as_uint(w1.y); ah[es][5] = (short)(u & 0xffff); al[es][5] = (short)(u >> 16);
        u = __float_as_uint(w1.z); ah[es][6] = (short)(u & 0xffff); al[es][6] = (short)(u >> 16);
        u = __float_as_uint(w1.w); ah[es][7] = (short)(u & 0xffff); al[es][7] = (short)(u >> 16);
    }
    f32x4 acc[16];
#pragma unroll
    for (int i = 0; i < 16; i++) acc[i] = (f32x4)0.f;

#pragma unroll
    for (int mc = 0; mc < 8; mc++) {
        __syncthreads();
#pragma unroll
        for (int jv = 0; jv < 8; jv++) {
            int flat = w * 8 + jv;
            int arr = flat >> 4, wi = flat & 15;
            const unsigned short* gb = arr ? El : Eh;
            const char* src = (const char*)gb
                + ((size_t)b * M + mc * 64 + wi * 4 + (lane >> 4)) * 256 + (lane & 15) * 16;
            gload16(src, lds + arr * 16384 + wi * 1024 + lane * 16);
        }
        __syncthreads();
#pragma unroll
        for (int ct = 0; ct < 2; ct++) {
            int mloc = mh * 32 + ct * 16 + row;
            int a = mc * 2 + ct;
            int rbase = mloc * 256;
            int sw = mloc & 7;
#pragma unroll
            for (int es = 0; es < 4; es++) {
                int ph = (4 * es + kg) ^ sw;
                s16x8 bh = *(const s16x8*)(lds + rbase + ph * 16);
                s16x8 bl = *(const s16x8*)(lds + 16384 + rbase + ph * 16);
                acc[a] = MFMA16(ah[es], bh, acc[a]);
                acc[a] = MFMA16(al[es], bh, acc[a]);
                acc[a] = MFMA16(ah[es], bl, acc[a]);
            }
        }
    }
    // epilogue: bias+tanh+clip, then softmax over m (cross-wave via LDS)
#pragma unroll
    for (int a = 0; a < 16; a++) {
        int mc = a >> 1, ct = a & 1;
        size_t mb = (size_t)mc * 64 + mh * 32 + ct * 16 + row;
#pragma unroll
        for (int r = 0; r < 4; r++) {
            int n = n0 + ng * 16 + kg * 4 + r;
            size_t idx = ((size_t)b * N + n) * M + mb;
            acc[a][r] = 10.f * tanhf(fmaf(acc[a][r], invs, -a2ls * cd[idx])) + ninf[idx];
        }
    }
    float mx[4], sm[4];
#pragma unroll
    for (int r = 0; r < 4; r++) {
        float m = acc[0][r];
#pragma unroll
        for (int a = 1; a < 16; a++) m = fmaxf(m, acc[a][r]);
#pragma unroll
        for (int s = 1; s < 16; s <<= 1) m = fmaxf(m, __shfl_xor(m, s, 64));
        mx[r] = m;
    }
    float* red = (float*)lds;
    int rl = ng * 16 + kg * 4;
    __syncthreads();   // done reading B-tiles; lds reused as reduction scratch
    if (row == 0) {
#pragma unroll
        for (int r = 0; r < 4; r++) red[(rl + r) * 2 + mh] = mx[r];
    }
    __syncthreads();
#pragma unroll
    for (int r = 0; r < 4; r++) {
        float m = fmaxf(red[(rl + r) * 2], red[(rl + r) * 2 + 1]);
        float s = 0.f;
#pragma unroll
        for (int a = 0; a < 16; a++) {
            float e = expf(acc[a][r] - m);
            acc[a][r] = e;
            s += e;
        }
#pragma unroll
        for (int sh = 1; sh < 16; sh <<= 1) s += __shfl_xor(s, sh, 64);
        sm[r] = s;
    }
    if (row == 0) {
#pragma unroll
        for (int r = 0; r < 4; r++) red[64 + (rl + r) * 2 + mh] = sm[r];
    }
    __syncthreads();
    float inv[4];
#pragma unroll
    for (int r = 0; r < 4; r++)
        inv[r] = 1.f / (red[64 + (rl + r) * 2] + red[64 + (rl + r) * 2 + 1]);
#pragma unroll
    for (int a = 0; a < 16; a++) {
        int mc = a >> 1, ct = a & 1;
        size_t mb = (size_t)mc * 64 + mh * 32 + ct * 16 + row;
#pragma unroll
        for (int r = 0; r < 4; r++) {
            int n = n0 + ng * 16 + kg * 4 + r;
            out[((size_t)b * N + n) * M + mb] = acc[a][r] * inv[r];
        }
    }
}

extern "C" void kernel_launch(void* const* d_in, const int* in_sizes, int n_in,
                              void* d_out, int out_size, void* d_ws, size_t ws_size,
                              hipStream_t stream) {
    const float* encl  = (const float*)d_in[0];
    const float* loadv = (const float*)d_in[1];
    const float* cdist = (const float*)d_in[2];
    const float* ls    = (const float*)d_in[3];
    const float* ninf  = (const float*)d_in[4];
    const float* enc   = (const float*)d_in[5];
    const float* Wq    = (const float*)d_in[6];
    const float* Wk    = (const float*)d_in[7];
    const float* Wv    = (const float*)d_in[8];
    const float* a1    = (const float*)d_in[9];
    const float* a2    = (const float*)d_in[10];
    char* ws = (char*)d_ws;
    unsigned short* EKT_hi  = (unsigned short*)(ws);
    unsigned short* EKT_lo  = (unsigned short*)(ws + 16777216);
    unsigned short* EKVT_hi = (unsigned short*)(ws + 33554432);
    unsigned short* EKVT_lo = (unsigned short*)(ws + 50331648);
    float*          SQ      = (float*)(ws + 67108864);
    unsigned short* Wk_hi   = (unsigned short*)(ws + 100663296);
    unsigned short* Wk_lo   = (unsigned short*)(ws + 100663296 + 32768);
    unsigned short* Wv_hi   = (unsigned short*)(ws + 100663296 + 65536);
    unsigned short* Wv_lo   = (unsigned short*)(ws + 100663296 + 98304);
    unsigned short* Wq_hi   = (unsigned short*)(ws + 100663296 + 131072);
    unsigned short* Wq_lo   = (unsigned short*)(ws + 100663296 + 163840);
    unsigned short* ENC_hi  = EKT_hi;   // reuse dead EKT region after k_numden
    unsigned short* ENC_lo  = EKT_lo;
    float* out = (float*)d_out;

    k_prep_w<<<192, 256, 0, stream>>>(Wk, Wv, Wq, Wk_hi, Wk_lo, Wv_hi, Wv_lo, Wq_hi, Wq_lo);
    k_kv<<<dim3(8, 128), 256, 0, stream>>>(enc, Wk_hi, Wk_lo, Wv_hi, Wv_lo,
                                           EKT_hi, EKT_lo, EKVT_hi, EKVT_lo);
    k_q<<<dim3(8, 128), 256, 0, stream>>>(encl, loadv, Wq, Wq_hi, Wq_lo, SQ);
    k_numden<<<1024, 256, 0, stream>>>(cdist, ninf, EKVT_hi, EKVT_lo,
                                       EKT_hi, EKT_lo, SQ, a1, ls);
    k_encsplit<<<4096, 256, 0, stream>>>(enc, ENC_hi, ENC_lo);
    k_score<<<2048, 256, 0, stream>>>(SQ, ENC_hi, ENC_lo, cdist, ninf, a2, ls, out);
}

// Round 4
// 376.653 us; speedup vs baseline: 2.3595x; 1.5656x over previous
//
#include <hip/hip_runtime.h>
#include <math.h>

#define B 128
#define N 512
#define M 512
#define D 128

typedef __attribute__((ext_vector_type(8))) short s16x8;
typedef __attribute__((ext_vector_type(4))) short s16x4;
typedef __attribute__((ext_vector_type(4))) float f32x4;

#define MFMA16(a, b, c) __builtin_amdgcn_mfma_f32_16x16x32_bf16(a, b, c, 0, 0, 0)

__device__ __forceinline__ void gload16(const void* g, void* l) {
    __builtin_amdgcn_global_load_lds(
        (const __attribute__((address_space(1))) unsigned int*)g,
        (__attribute__((address_space(3))) unsigned int*)l, 16, 0, 0);
}

__device__ __forceinline__ float fast_tanh(float x) {
    x = fminf(fmaxf(x, -15.f), 15.f);
    float E = __expf(2.f * x);
    return 1.f - 2.f / (E + 1.f);
}

// Truncation split: x ~= hi + lo
__device__ __forceinline__ void fsplit(float x, short& h, short& l) {
    unsigned u = __float_as_uint(x);
    h = (short)(u >> 16);
    float fh = __uint_as_float(u & 0xffff0000u);
    l = (short)(__float_as_uint(x - fh) >> 16);
}

__device__ __forceinline__ void fsplit8(float4 x0, float4 x1, s16x8& h, s16x8& l) {
    short a, b;
    fsplit(x0.x, a, b); h[0] = a; l[0] = b;
    fsplit(x0.y, a, b); h[1] = a; l[1] = b;
    fsplit(x0.z, a, b); h[2] = a; l[2] = b;
    fsplit(x0.w, a, b); h[3] = a; l[3] = b;
    fsplit(x1.x, a, b); h[4] = a; l[4] = b;
    fsplit(x1.y, a, b); h[5] = a; l[5] = b;
    fsplit(x1.z, a, b); h[6] = a; l[6] = b;
    fsplit(x1.w, a, b); h[7] = a; l[7] = b;
}

__global__ void k_prep_w(const float* __restrict__ Wk, const float* __restrict__ Wv,
                         const float* __restrict__ Wq,
                         unsigned short* __restrict__ Wk_hi, unsigned short* __restrict__ Wk_lo,
                         unsigned short* __restrict__ Wv_hi, unsigned short* __restrict__ Wv_lo,
                         unsigned short* __restrict__ Wq_hi, unsigned short* __restrict__ Wq_lo) {
    int i = blockIdx.x * 256 + threadIdx.x;  // 0..49151
    short h, l;
    if (i < 16384) {
        fsplit(Wk[i], h, l); Wk_hi[i] = (unsigned short)h; Wk_lo[i] = (unsigned short)l;
    } else if (i < 32768) {
        int j = i - 16384;
        fsplit(Wv[j], h, l); Wv_hi[j] = (unsigned short)h; Wv_lo[j] = (unsigned short)l;
    } else {
        int j = i - 32768; int e = j >> 7, d = j & 127;
        fsplit(Wq[e * 129 + d], h, l); Wq_hi[j] = (unsigned short)h; Wq_lo[j] = (unsigned short)l;
    }
}

// k = enc@Wk^T, v = enc@Wv^T; store EK^T/(EK*V)^T bf16 hi/lo [b][e][m],
// SWIZZLED: within each 32-m group, 8-m chunk c stored at c ^ (e&3).
__global__ __launch_bounds__(256) void k_kv(const float* __restrict__ enc,
        const unsigned short* __restrict__ Wk_hi, const unsigned short* __restrict__ Wk_lo,
        const unsigned short* __restrict__ Wv_hi, const unsigned short* __restrict__ Wv_lo,
        unsigned short* __restrict__ EKT_hi, unsigned short* __restrict__ EKT_lo,
        unsigned short* __restrict__ EKVT_hi, unsigned short* __restrict__ EKVT_lo) {
    int b = blockIdx.y;
    int wave = threadIdx.x >> 6, lane = threadIdx.x & 63;
    int row = lane & 15, kg = lane >> 4;
    int m0 = blockIdx.x * 64 + wave * 16;
    f32x4 acc[16];
#pragma unroll
    for (int i = 0; i < 16; i++) acc[i] = (f32x4)0.f;
    const float* ap = enc + ((size_t)b * M + m0 + row) * D + kg * 8;
#pragma unroll
    for (int ks = 0; ks < 4; ks++) {
        float4 x0 = *(const float4*)(ap + ks * 32);
        float4 x1 = *(const float4*)(ap + ks * 32 + 4);
        s16x8 ah, al;
        fsplit8(x0, x1, ah, al);
        int wb = ks * 32 + kg * 8;
#pragma unroll
        for (int ct = 0; ct < 8; ct++) {
            int e = ct * 16 + row;
            s16x8 bh = *(const s16x8*)(Wk_hi + e * D + wb);
            s16x8 bl = *(const s16x8*)(Wk_lo + e * D + wb);
            acc[ct] = MFMA16(ah, bh, acc[ct]);
            acc[ct] = MFMA16(al, bh, acc[ct]);
            acc[ct] = MFMA16(ah, bl, acc[ct]);
            bh = *(const s16x8*)(Wv_hi + e * D + wb);
            bl = *(const s16x8*)(Wv_lo + e * D + wb);
            acc[8 + ct] = MFMA16(ah, bh, acc[8 + ct]);
            acc[8 + ct] = MFMA16(al, bh, acc[8 + ct]);
            acc[8 + ct] = MFMA16(ah, bl, acc[8 + ct]);
        }
    }
#pragma unroll
    for (int ct = 0; ct < 8; ct++) {
        int e = ct * 16 + row;
        s16x4 ekh, ekl, evh, evl;
#pragma unroll
        for (int r = 0; r < 4; r++) {
            float ek = __expf(acc[ct][r]);
            float ev = ek * acc[8 + ct][r];
            short h, l;
            fsplit(ek, h, l); ekh[r] = h; ekl[r] = l;
            fsplit(ev, h, l); evh[r] = h; evl[r] = l;
        }
        int m = m0 + kg * 4;
        int chunk = (m & 31) >> 3;
        int p = chunk ^ (e & 3);
        size_t o = ((size_t)b * D + e) * M + (size_t)(m & ~31) + p * 8 + (m & 7);
        *(s16x4*)(EKT_hi + o) = ekh;
        *(s16x4*)(EKT_lo + o) = ekl;
        *(s16x4*)(EKVT_hi + o) = evh;
        *(s16x4*)(EKVT_lo + o) = evl;
    }
}

// q = [encl, load]@Wq^T; SQ = sigmoid(q) f32 [b][n][e]
__global__ __launch_bounds__(256) void k_q(const float* __restrict__ encl,
        const float* __restrict__ loadv, const float* __restrict__ Wq,
        const unsigned short* __restrict__ Wq_hi, const unsigned short* __restrict__ Wq_lo,
        float* __restrict__ SQ) {
    int b = blockIdx.y;
    int wave = threadIdx.x >> 6, lane = threadIdx.x & 63;
    int row = lane & 15, kg = lane >> 4;
    int n0 = blockIdx.x * 64 + wave * 16;
    f32x4 acc[8];
#pragma unroll
    for (int i = 0; i < 8; i++) acc[i] = (f32x4)0.f;
    const float* ap = encl + ((size_t)b * N + n0 + row) * D + kg * 8;
#pragma unroll
    for (int ks = 0; ks < 4; ks++) {
        float4 x0 = *(const float4*)(ap + ks * 32);
        float4 x1 = *(const float4*)(ap + ks * 32 + 4);
        s16x8 ah, al;
        fsplit8(x0, x1, ah, al);
        int wb = ks * 32 + kg * 8;
#pragma unroll
        for (int ct = 0; ct < 8; ct++) {
            int e = ct * 16 + row;
            s16x8 bh = *(const s16x8*)(Wq_hi + e * D + wb);
            s16x8 bl = *(const s16x8*)(Wq_lo + e * D + wb);
            acc[ct] = MFMA16(ah, bh, acc[ct]);
            acc[ct] = MFMA16(al, bh, acc[ct]);
            acc[ct] = MFMA16(ah, bl, acc[ct]);
        }
    }
#pragma unroll
    for (int r = 0; r < 4; r++) {
        int n = n0 + kg * 4 + r;
        float lv = loadv[(size_t)b * N + n];
        size_t ro = ((size_t)b * N + n) * D;
#pragma unroll
        for (int ct = 0; ct < 8; ct++) {
            int e = ct * 16 + row;
            float q = acc[ct][r] + lv * Wq[e * 129 + 128];
            SQ[ro + e] = 1.f / (1.f + __expf(-q));
        }
    }
}

// num=EB@EKV, den=EB@EK. Double-buffered LDS staging (1 barrier/phase),
// A-operand (cd/ninf) register-prefetched one phase ahead.
__global__ __launch_bounds__(256) void k_numden(
        const float* __restrict__ cd, const float* __restrict__ ninf,
        const unsigned short* __restrict__ EKVT_hi, const unsigned short* __restrict__ EKVT_lo,
        const unsigned short* __restrict__ EKT_hi, const unsigned short* __restrict__ EKT_lo,
        float* __restrict__ SQ,
        const float* __restrict__ a1p, const float* __restrict__ lsp) {
    int o = blockIdx.x;
    int jj = o >> 3;
    int b = (o & 7) + ((jj >> 3) << 3);   // 16 b's per XCD
    int nb = jj & 7;
    int w = threadIdx.x >> 6, lane = threadIdx.x & 63;
    int row = lane & 15, kg = lane >> 4;
    int n0 = nb * 64 + w * 16;
    __shared__ __align__(16) char lds[2][32768];  // dbuf x [4 arrays][128 e][64 B]
    float a1ls = a1p[0] * lsp[0];
    const char* gbase = (const char*)(w == 0 ? EKVT_hi : w == 1 ? EKVT_lo
                                    : w == 2 ? EKT_hi : EKT_lo)
                        + (size_t)b * D * M * 2;
    int srow = lane >> 2, schunk = lane & 3;
    f32x4 acc[16];
#pragma unroll
    for (int i = 0; i < 16; i++) acc[i] = (f32x4)0.f;
    const float* cdp = cd + ((size_t)b * N + n0 + row) * M + kg * 8;
    const float* nfp = ninf + ((size_t)b * N + n0 + row) * M + kg * 8;
    int rb = row * 64 + ((kg ^ (row & 3)) << 4);

#define STAGE_ND(buf, mt)                                                          \
    _Pragma("unroll")                                                              \
    for (int jv = 0; jv < 8; jv++) {                                               \
        gload16(gbase + (size_t)(jv * 16 + srow) * 1024 + (mt) * 64 + schunk * 16, \
                lds[buf] + w * 8192 + jv * 1024 + lane * 16);                      \
    }

    // prologue: A-regs for phase 0, stage tile 0
    float4 c0 = *(const float4*)(cdp), c1 = *(const float4*)(cdp + 4);
    float4 f0 = *(const float4*)(nfp), f1 = *(const float4*)(nfp + 4);
    STAGE_ND(0, 0)

#pragma unroll
    for (int mt = 0; mt < 16; mt++) {
        int cur = mt & 1;
        __syncthreads();   // drains stages of buf[cur] (issued a full phase ago)
        // EB from prefetched regs
        float4 e0, e1;
        e0.x = __expf(fmaf(-a1ls, c0.x, f0.x));
        e0.y = __expf(fmaf(-a1ls, c0.y, f0.y));
        e0.z = __expf(fmaf(-a1ls, c0.z, f0.z));
        e0.w = __expf(fmaf(-a1ls, c0.w, f0.w));
        e1.x = __expf(fmaf(-a1ls, c1.x, f1.x));
        e1.y = __expf(fmaf(-a1ls, c1.y, f1.y));
        e1.z = __expf(fmaf(-a1ls, c1.z, f1.z));
        e1.w = __expf(fmaf(-a1ls, c1.w, f1.w));
        s16x8 ah, al;
        fsplit8(e0, e1, ah, al);
        // prefetch next phase's A + stage next tile (fly under MFMAs)
        if (mt < 15) {
            int m = (mt + 1) * 32;
            c0 = *(const float4*)(cdp + m); c1 = *(const float4*)(cdp + m + 4);
            f0 = *(const float4*)(nfp + m); f1 = *(const float4*)(nfp + m + 4);
            STAGE_ND(cur ^ 1, mt + 1)
        }
#pragma unroll
        for (int ct = 0; ct < 8; ct++) {
            int ro = ct * 1024 + rb;
            s16x8 bh = *(const s16x8*)(&lds[cur][ro]);             // EKVT_hi
            s16x8 bl = *(const s16x8*)(&lds[cur][8192 + ro]);      // EKVT_lo
            acc[ct] = MFMA16(ah, bh, acc[ct]);
            acc[ct] = MFMA16(al, bh, acc[ct]);
            acc[ct] = MFMA16(ah, bl, acc[ct]);
            bh = *(const s16x8*)(&lds[cur][16384 + ro]);           // EKT_hi
            bl = *(const s16x8*)(&lds[cur][24576 + ro]);           // EKT_lo
            acc[8 + ct] = MFMA16(ah, bh, acc[8 + ct]);
            acc[8 + ct] = MFMA16(al, bh, acc[8 + ct]);
            acc[8 + ct] = MFMA16(ah, bl, acc[8 + ct]);
        }
    }
#pragma unroll
    for (int r = 0; r < 4; r++) {
        int n = n0 + kg * 4 + r;
        size_t ro = ((size_t)b * N + n) * D;
#pragma unroll
        for (int ct = 0; ct < 8; ct++) {
            int e = ct * 16 + row;
            float num = acc[ct][r], den = acc[8 + ct][r];
            float ww = (den != 0.f) ? num / den : 0.f;
            float aafm = SQ[ro + e] * ww;
            unsigned u = __float_as_uint(aafm);
            unsigned hi = u >> 16;
            float fh = __uint_as_float(u & 0xffff0000u);
            unsigned lo = __float_as_uint(aafm - fh) >> 16;
            SQ[ro + e] = __uint_as_float(hi | (lo << 16));
        }
    }
}

// Split enc -> bf16 hi/lo [b][m][128e], SWIZZLED: 8-e chunk c at c ^ (m&7)
__global__ void k_encsplit(const float* __restrict__ enc,
                           unsigned short* __restrict__ Eh, unsigned short* __restrict__ El) {
    size_t i = (size_t)blockIdx.x * 256 + threadIdx.x;   // chunk id
    size_t bm = i >> 4;
    int c = (int)(i & 15);
    int m = (int)(bm & 511);
    int p = c ^ (m & 7);
    const float* src = enc + bm * 128 + c * 8;
    float4 x0 = *(const float4*)(src);
    float4 x1 = *(const float4*)(src + 4);
    s16x8 h, l;
    fsplit8(x0, x1, h, l);
    *(s16x8*)(Eh + bm * 128 + p * 8) = h;
    *(s16x8*)(El + bm * 128 + p * 8) = l;
}

// score = AAFM@enc^T, dbuf LDS staging, in-loop bias+tanh epilogue, fused softmax.
__global__ __launch_bounds__(256) void k_score(
        const float* __restrict__ AAFM,
        const unsigned short* __restrict__ Eh, const unsigned short* __restrict__ El,
        const float* __restrict__ cd, const float* __restrict__ ninf,
        const float* __restrict__ a2p, const float* __restrict__ lsp,
        float* __restrict__ out) {
    int o = blockIdx.x;
    int j = o >> 3;
    int b = (o & 7) + ((j >> 4) << 3);
    int nb = j & 15;
    int n0 = nb * 32;
    int w = threadIdx.x >> 6, lane = threadIdx.x & 63;
    int row = lane & 15, kg = lane >> 4;
    int ng = w >> 1, mh = w & 1;
    __shared__ __align__(16) char lds[2][32768];  // dbuf x [hi|lo][64 m][256 B]
    __shared__ float redm[64][2];
    __shared__ float reds[64][2];
    float a2ls = a2p[0] * lsp[0];
    const float invs = 0.08838834764831845f;

    // A preload: 16 rows of packed AAFM (hi|lo<<16)
    const float* apk = AAFM + ((size_t)b * N + n0 + ng * 16 + row) * D + kg * 8;
    s16x8 ah[4], al[4];
#pragma unroll
    for (int es = 0; es < 4; es++) {
        float4 w0 = *(const float4*)(apk + es * 32);
        float4 w1 = *(const float4*)(apk + es * 32 + 4);
        unsigned u;
        u = __float_as_uint(w0.x); ah[es][0] = (short)(u & 0xffff); al[es][0] = (short)(u >> 16);
        u = __float_as_uint(w0.y); ah[es][1] = (short)(u & 0xffff); al[es][1] = (short)(u >> 16);
        u = __float_as_uint(w0.z); ah[es][2] = (short)(u & 0xffff); al[es][2] = (short)(u >> 16);
        u = __float_as_uint(w0.w); ah[es][3] = (short)(u & 0xffff); al[es][3] = (short)(u >> 16);
        u = __float_as_uint(w1.x); ah[es][4] = (short)(u & 0xffff); al[es][4] = (short)(u >> 16);
        u = __float_as_uint(w1.y); ah[es][5] = (short)(u & 0xffff); al[es][5] = (short)(u >> 16);
        u = __float_as_uint(w1.z); ah[es][6] = (short)(u & 0xffff); al[es][6] = (short)(u >> 16);
        u = __float_as_uint(w1.w); ah[es][7] = (short)(u & 0xffff); al[es][7] = (short)(u >> 16);
    }
    f32x4 acc[16];
#pragma unroll
    for (int i = 0; i < 16; i++) acc[i] = (f32x4)0.f;

#define STAGE_SC(buf, mc)                                                              \
    _Pragma("unroll")                                                                  \
    for (int jv = 0; jv < 8; jv++) {                                                   \
        int flat = w * 8 + jv;                                                         \
        int arr = flat >> 4, wi = flat & 15;                                           \
        const unsigned short* gb = arr ? El : Eh;                                      \
        const char* src = (const char*)gb                                             \
            + ((size_t)b * M + (mc) * 64 + wi * 4 + kg) * 256 + row * 16;              \
        gload16(src, lds[buf] + arr * 16384 + wi * 1024 + lane * 16);                  \
    }

    STAGE_SC(0, 0)
#pragma unroll
    for (int mc = 0; mc < 8; mc++) {
        int cur = mc & 1;
        __syncthreads();   // drains stages of buf[cur] (issued a full phase ago)
        // MFMA on tile cur
#pragma unroll
        for (int ct = 0; ct < 2; ct++) {
            int mloc = mh * 32 + ct * 16 + row;
            int a = mc * 2 + ct;
            int rbase = mloc * 256;
            int sw = mloc & 7;
#pragma unroll
            for (int es = 0; es < 4; es++) {
                int ph = (4 * es + kg) ^ sw;
                s16x8 bh = *(const s16x8*)(&lds[cur][rbase + ph * 16]);
                s16x8 bl = *(const s16x8*)(&lds[cur][16384 + rbase + ph * 16]);
                acc[a] = MFMA16(ah[es], bh, acc[a]);
                acc[a] = MFMA16(al[es], bh, acc[a]);
                acc[a] = MFMA16(ah[es], bl, acc[a]);
            }
        }
        // issue this tile's cd/ninf loads
        float cdv[2][4], nfv[2][4];
#pragma unroll
        for (int ct = 0; ct < 2; ct++)
#pragma unroll
            for (int r = 0; r < 4; r++) {
                size_t idx = ((size_t)b * N + n0 + ng * 16 + kg * 4 + r) * M
                           + (size_t)mc * 64 + mh * 32 + ct * 16 + row;
                cdv[ct][r] = cd[idx];
                nfv[ct][r] = ninf[idx];
            }
        // stage next tile (completes during tanh + next barrier)
        if (mc < 7) STAGE_SC(cur ^ 1, mc + 1)
        // bias + tanh + mask for this tile
#pragma unroll
        for (int ct = 0; ct < 2; ct++) {
            int a = mc * 2 + ct;
#pragma unroll
            for (int r = 0; r < 4; r++) {
                acc[a][r] = 10.f * fast_tanh(fmaf(acc[a][r], invs, -a2ls * cdv[ct][r]))
                          + nfv[ct][r];
            }
        }
    }
    // softmax over m (cross-wave via dedicated LDS scratch)
    float mx[4], sm[4];
#pragma unroll
    for (int r = 0; r < 4; r++) {
        float m = acc[0][r];
#pragma unroll
        for (int a = 1; a < 16; a++) m = fmaxf(m, acc[a][r]);
#pragma unroll
        for (int s = 1; s < 16; s <<= 1) m = fmaxf(m, __shfl_xor(m, s, 64));
        mx[r] = m;
    }
    int rl = ng * 16 + kg * 4;
    if (row == 0) {
#pragma unroll
        for (int r = 0; r < 4; r++) redm[rl + r][mh] = mx[r];
    }
    __syncthreads();
#pragma unroll
    for (int r = 0; r < 4; r++) {
        float m = fmaxf(redm[rl + r][0], redm[rl + r][1]);
        float s = 0.f;
#pragma unroll
        for (int a = 0; a < 16; a++) {
            float e = __expf(acc[a][r] - m);
            acc[a][r] = e;
            s += e;
        }
#pragma unroll
        for (int sh = 1; sh < 16; sh <<= 1) s += __shfl_xor(s, sh, 64);
        sm[r] = s;
    }
    if (row == 0) {
#pragma unroll
        for (int r = 0; r < 4; r++) reds[rl + r][mh] = sm[r];
    }
    __syncthreads();
    float inv[4];
#pragma unroll
    for (int r = 0; r < 4; r++)
        inv[r] = 1.f / (reds[rl + r][0] + reds[rl + r][1]);
#pragma unroll
    for (int a = 0; a < 16; a++) {
        int mc = a >> 1, ct = a & 1;
        size_t mb = (size_t)mc * 64 + mh * 32 + ct * 16 + row;
#pragma unroll
        for (int r = 0; r < 4; r++) {
            int n = n0 + ng * 16 + kg * 4 + r;
            out[((size_t)b * N + n) * M + mb] = acc[a][r] * inv[r];
        }
    }
}

extern "C" void kernel_launch(void* const* d_in, const int* in_sizes, int n_in,
                              void* d_out, int out_size, void* d_ws, size_t ws_size,
                              hipStream_t stream) {
    const float* encl  = (const float*)d_in[0];
    const float* loadv = (const float*)d_in[1];
    const float* cdist = (const float*)d_in[2];
    const float* ls    = (const float*)d_in[3];
    const float* ninf  = (const float*)d_in[4];
    const float* enc   = (const float*)d_in[5];
    const float* Wq    = (const float*)d_in[6];
    const float* Wk    = (const float*)d_in[7];
    const float* Wv    = (const float*)d_in[8];
    const float* a1    = (const float*)d_in[9];
    const float* a2    = (const float*)d_in[10];
    char* ws = (char*)d_ws;
    unsigned short* EKT_hi  = (unsigned short*)(ws);
    unsigned short* EKT_lo  = (unsigned short*)(ws + 16777216);
    unsigned short* EKVT_hi = (unsigned short*)(ws + 33554432);
    unsigned short* EKVT_lo = (unsigned short*)(ws + 50331648);
    float*          SQ      = (float*)(ws + 67108864);
    unsigned short* Wk_hi   = (unsigned short*)(ws + 100663296);
    unsigned short* Wk_lo   = (unsigned short*)(ws + 100663296 + 32768);
    unsigned short* Wv_hi   = (unsigned short*)(ws + 100663296 + 65536);
    unsigned short* Wv_lo   = (unsigned short*)(ws + 100663296 + 98304);
    unsigned short* Wq_hi   = (unsigned short*)(ws + 100663296 + 131072);
    unsigned short* Wq_lo   = (unsigned short*)(ws + 100663296 + 163840);
    unsigned short* ENC_hi  = EKT_hi;   // reuse dead EKT region after k_numden
    unsigned short* ENC_lo  = EKT_lo;
    float* out = (float*)d_out;

    k_prep_w<<<192, 256, 0, stream>>>(Wk, Wv, Wq, Wk_hi, Wk_lo, Wv_hi, Wv_lo, Wq_hi, Wq_lo);
    k_kv<<<dim3(8, 128), 256, 0, stream>>>(enc, Wk_hi, Wk_lo, Wv_hi, Wv_lo,
                                           EKT_hi, EKT_lo, EKVT_hi, EKVT_lo);
    k_q<<<dim3(8, 128), 256, 0, stream>>>(encl, loadv, Wq, Wq_hi, Wq_lo, SQ);
    k_numden<<<1024, 256, 0, stream>>>(cdist, ninf, EKVT_hi, EKVT_lo,
                                       EKT_hi, EKT_lo, SQ, a1, ls);
    k_encsplit<<<4096, 256, 0, stream>>>(enc, ENC_hi, ENC_lo);
    k_score<<<2048, 256, 0, stream>>>(SQ, ENC_hi, ENC_lo, cdist, ninf, a2, ls, out);
}

// Round 5
// 363.461 us; speedup vs baseline: 2.4452x; 1.0363x over previous
//
#include <hip/hip_runtime.h>
#include <math.h>

#define B 128
#define N 512
#define M 512
#define D 128

typedef __attribute__((ext_vector_type(8))) short s16x8;
typedef __attribute__((ext_vector_type(4))) short s16x4;
typedef __attribute__((ext_vector_type(4))) float f32x4;

#define MFMA16(a, b, c) __builtin_amdgcn_mfma_f32_16x16x32_bf16(a, b, c, 0, 0, 0)

__device__ __forceinline__ void gload16(const void* g, void* l) {
    __builtin_amdgcn_global_load_lds(
        (const __attribute__((address_space(1))) unsigned int*)g,
        (__attribute__((address_space(3))) unsigned int*)l, 16, 0, 0);
}

__device__ __forceinline__ float fast_tanh(float x) {
    x = fminf(fmaxf(x, -15.f), 15.f);
    float E = __expf(2.f * x);
    return 1.f - 2.f / (E + 1.f);
}

// Truncation split: x ~= hi + lo
__device__ __forceinline__ void fsplit(float x, short& h, short& l) {
    unsigned u = __float_as_uint(x);
    h = (short)(u >> 16);
    float fh = __uint_as_float(u & 0xffff0000u);
    l = (short)(__float_as_uint(x - fh) >> 16);
}

__device__ __forceinline__ void fsplit8(float4 x0, float4 x1, s16x8& h, s16x8& l) {
    short a, b;
    fsplit(x0.x, a, b); h[0] = a; l[0] = b;
    fsplit(x0.y, a, b); h[1] = a; l[1] = b;
    fsplit(x0.z, a, b); h[2] = a; l[2] = b;
    fsplit(x0.w, a, b); h[3] = a; l[3] = b;
    fsplit(x1.x, a, b); h[4] = a; l[4] = b;
    fsplit(x1.y, a, b); h[5] = a; l[5] = b;
    fsplit(x1.z, a, b); h[6] = a; l[6] = b;
    fsplit(x1.w, a, b); h[7] = a; l[7] = b;
}

// EB = exp(-a1ls*cd + ninf) for 8 elements, split to bf16 hi/lo
__device__ __forceinline__ void ebsplit(float4 c0, float4 c1, float4 f0, float4 f1,
                                        float a1ls, s16x8& ah, s16x8& al) {
    float4 e0, e1;
    e0.x = __expf(fmaf(-a1ls, c0.x, f0.x));
    e0.y = __expf(fmaf(-a1ls, c0.y, f0.y));
    e0.z = __expf(fmaf(-a1ls, c0.z, f0.z));
    e0.w = __expf(fmaf(-a1ls, c0.w, f0.w));
    e1.x = __expf(fmaf(-a1ls, c1.x, f1.x));
    e1.y = __expf(fmaf(-a1ls, c1.y, f1.y));
    e1.z = __expf(fmaf(-a1ls, c1.z, f1.z));
    e1.w = __expf(fmaf(-a1ls, c1.w, f1.w));
    fsplit8(e0, e1, ah, al);
}

__global__ void k_prep_w(const float* __restrict__ Wk, const float* __restrict__ Wv,
                         const float* __restrict__ Wq,
                         unsigned short* __restrict__ Wk_hi, unsigned short* __restrict__ Wk_lo,
                         unsigned short* __restrict__ Wv_hi, unsigned short* __restrict__ Wv_lo,
                         unsigned short* __restrict__ Wq_hi, unsigned short* __restrict__ Wq_lo) {
    int i = blockIdx.x * 256 + threadIdx.x;  // 0..49151
    short h, l;
    if (i < 16384) {
        fsplit(Wk[i], h, l); Wk_hi[i] = (unsigned short)h; Wk_lo[i] = (unsigned short)l;
    } else if (i < 32768) {
        int j = i - 16384;
        fsplit(Wv[j], h, l); Wv_hi[j] = (unsigned short)h; Wv_lo[j] = (unsigned short)l;
    } else {
        int j = i - 32768; int e = j >> 7, d = j & 127;
        fsplit(Wq[e * 129 + d], h, l); Wq_hi[j] = (unsigned short)h; Wq_lo[j] = (unsigned short)l;
    }
}

// k = enc@Wk^T, v = enc@Wv^T; store EK^T/(EK*V)^T bf16 hi/lo [b][e][m],
// SWIZZLED: within each 32-m group, 8-m chunk c stored at c ^ (e&3).
__global__ __launch_bounds__(256) void k_kv(const float* __restrict__ enc,
        const unsigned short* __restrict__ Wk_hi, const unsigned short* __restrict__ Wk_lo,
        const unsigned short* __restrict__ Wv_hi, const unsigned short* __restrict__ Wv_lo,
        unsigned short* __restrict__ EKT_hi, unsigned short* __restrict__ EKT_lo,
        unsigned short* __restrict__ EKVT_hi, unsigned short* __restrict__ EKVT_lo) {
    int b = blockIdx.y;
    int wave = threadIdx.x >> 6, lane = threadIdx.x & 63;
    int row = lane & 15, kg = lane >> 4;
    int m0 = blockIdx.x * 64 + wave * 16;
    f32x4 acc[16];
#pragma unroll
    for (int i = 0; i < 16; i++) acc[i] = (f32x4)0.f;
    const float* ap = enc + ((size_t)b * M + m0 + row) * D + kg * 8;
#pragma unroll
    for (int ks = 0; ks < 4; ks++) {
        float4 x0 = *(const float4*)(ap + ks * 32);
        float4 x1 = *(const float4*)(ap + ks * 32 + 4);
        s16x8 ah, al;
        fsplit8(x0, x1, ah, al);
        int wb = ks * 32 + kg * 8;
#pragma unroll
        for (int ct = 0; ct < 8; ct++) {
            int e = ct * 16 + row;
            s16x8 bh = *(const s16x8*)(Wk_hi + e * D + wb);
            s16x8 bl = *(const s16x8*)(Wk_lo + e * D + wb);
            acc[ct] = MFMA16(ah, bh, acc[ct]);
            acc[ct] = MFMA16(al, bh, acc[ct]);
            acc[ct] = MFMA16(ah, bl, acc[ct]);
            bh = *(const s16x8*)(Wv_hi + e * D + wb);
            bl = *(const s16x8*)(Wv_lo + e * D + wb);
            acc[8 + ct] = MFMA16(ah, bh, acc[8 + ct]);
            acc[8 + ct] = MFMA16(al, bh, acc[8 + ct]);
            acc[8 + ct] = MFMA16(ah, bl, acc[8 + ct]);
        }
    }
#pragma unroll
    for (int ct = 0; ct < 8; ct++) {
        int e = ct * 16 + row;
        s16x4 ekh, ekl, evh, evl;
#pragma unroll
        for (int r = 0; r < 4; r++) {
            float ek = __expf(acc[ct][r]);
            float ev = ek * acc[8 + ct][r];
            short h, l;
            fsplit(ek, h, l); ekh[r] = h; ekl[r] = l;
            fsplit(ev, h, l); evh[r] = h; evl[r] = l;
        }
        int m = m0 + kg * 4;
        int chunk = (m & 31) >> 3;
        int p = chunk ^ (e & 3);
        size_t o = ((size_t)b * D + e) * M + (size_t)(m & ~31) + p * 8 + (m & 7);
        *(s16x4*)(EKT_hi + o) = ekh;
        *(s16x4*)(EKT_lo + o) = ekl;
        *(s16x4*)(EKVT_hi + o) = evh;
        *(s16x4*)(EKVT_lo + o) = evl;
    }
}

// q = [encl, load]@Wq^T; SQ = sigmoid(q) f32 [b][n][e]
__global__ __launch_bounds__(256) void k_q(const float* __restrict__ encl,
        const float* __restrict__ loadv, const float* __restrict__ Wq,
        const unsigned short* __restrict__ Wq_hi, const unsigned short* __restrict__ Wq_lo,
        float* __restrict__ SQ) {
    int b = blockIdx.y;
    int wave = threadIdx.x >> 6, lane = threadIdx.x & 63;
    int row = lane & 15, kg = lane >> 4;
    int n0 = blockIdx.x * 64 + wave * 16;
    f32x4 acc[8];
#pragma unroll
    for (int i = 0; i < 8; i++) acc[i] = (f32x4)0.f;
    const float* ap = encl + ((size_t)b * N + n0 + row) * D + kg * 8;
#pragma unroll
    for (int ks = 0; ks < 4; ks++) {
        float4 x0 = *(const float4*)(ap + ks * 32);
        float4 x1 = *(const float4*)(ap + ks * 32 + 4);
        s16x8 ah, al;
        fsplit8(x0, x1, ah, al);
        int wb = ks * 32 + kg * 8;
#pragma unroll
        for (int ct = 0; ct < 8; ct++) {
            int e = ct * 16 + row;
            s16x8 bh = *(const s16x8*)(Wq_hi + e * D + wb);
            s16x8 bl = *(const s16x8*)(Wq_lo + e * D + wb);
            acc[ct] = MFMA16(ah, bh, acc[ct]);
            acc[ct] = MFMA16(al, bh, acc[ct]);
            acc[ct] = MFMA16(ah, bl, acc[ct]);
        }
    }
#pragma unroll
    for (int r = 0; r < 4; r++) {
        int n = n0 + kg * 4 + r;
        float lv = loadv[(size_t)b * N + n];
        size_t ro = ((size_t)b * N + n) * D;
#pragma unroll
        for (int ct = 0; ct < 8; ct++) {
            int e = ct * 16 + row;
            float q = acc[ct][r] + lv * Wq[e * 129 + 128];
            SQ[ro + e] = 1.f / (1.f + __expf(-q));
        }
    }
}

// num=EB@EKV, den=EB@EK. Each wave owns 32 n-rows (2 sets) -> B-tile LDS reads
// amortized 2x. Grid 512 = 128 b x 4 nb (XCD-bijective), 1 generation.
__global__ __launch_bounds__(256, 2) void k_numden(
        const float* __restrict__ cd, const float* __restrict__ ninf,
        const unsigned short* __restrict__ EKVT_hi, const unsigned short* __restrict__ EKVT_lo,
        const unsigned short* __restrict__ EKT_hi, const unsigned short* __restrict__ EKT_lo,
        float* __restrict__ SQ,
        const float* __restrict__ a1p, const float* __restrict__ lsp) {
    int o = blockIdx.x;
    int xcd = o & 7, j = o >> 3;
    int b = ((j >> 2) << 3) + xcd;     // 16 b's per XCD
    int nb = j & 3;
    int w = threadIdx.x >> 6, lane = threadIdx.x & 63;
    int row = lane & 15, kg = lane >> 4;
    int n0 = nb * 128 + w * 32;
    __shared__ __align__(16) char lds[2][32768];  // dbuf x [4 arrays][128 e][64 B]
    float a1ls = a1p[0] * lsp[0];
    const char* gbase = (const char*)(w == 0 ? EKVT_hi : w == 1 ? EKVT_lo
                                    : w == 2 ? EKT_hi : EKT_lo)
                        + (size_t)b * D * M * 2;
    int srow = lane >> 2, schunk = lane & 3;
    f32x4 accN[2][8], accD[2][8];
#pragma unroll
    for (int s = 0; s < 2; s++)
#pragma unroll
        for (int i = 0; i < 8; i++) { accN[s][i] = (f32x4)0.f; accD[s][i] = (f32x4)0.f; }
    const float* cdp0 = cd + ((size_t)b * N + n0 + row) * M + kg * 8;
    const float* nfp0 = ninf + ((size_t)b * N + n0 + row) * M + kg * 8;
    const float* cdp1 = cdp0 + (size_t)16 * M;
    const float* nfp1 = nfp0 + (size_t)16 * M;
    int rb = row * 64 + ((kg ^ (row & 3)) << 4);

#define STAGE_ND(buf, mt)                                                          \
    _Pragma("unroll")                                                              \
    for (int jv = 0; jv < 8; jv++) {                                               \
        gload16(gbase + (size_t)(jv * 16 + srow) * 1024 + (mt) * 64 + schunk * 16, \
                lds[buf] + w * 8192 + jv * 1024 + lane * 16);                      \
    }

    // prologue: A-regs for phase 0 (both sets), stage tile 0
    float4 c00 = *(const float4*)(cdp0), c01 = *(const float4*)(cdp0 + 4);
    float4 f00 = *(const float4*)(nfp0), f01 = *(const float4*)(nfp0 + 4);
    float4 c10 = *(const float4*)(cdp1), c11 = *(const float4*)(cdp1 + 4);
    float4 f10 = *(const float4*)(nfp1), f11 = *(const float4*)(nfp1 + 4);
    STAGE_ND(0, 0)

#pragma unroll 2
    for (int mt = 0; mt < 16; mt++) {
        int cur = mt & 1;
        __syncthreads();   // drains stages of buf[cur] (issued a full phase ago)
        s16x8 ah0, al0, ah1, al1;
        ebsplit(c00, c01, f00, f01, a1ls, ah0, al0);
        ebsplit(c10, c11, f10, f11, a1ls, ah1, al1);
        // prefetch next phase's A (both sets) + stage next tile
        if (mt < 15) {
            int m = (mt + 1) * 32;
            c00 = *(const float4*)(cdp0 + m); c01 = *(const float4*)(cdp0 + m + 4);
            f00 = *(const float4*)(nfp0 + m); f01 = *(const float4*)(nfp0 + m + 4);
            c10 = *(const float4*)(cdp1 + m); c11 = *(const float4*)(cdp1 + m + 4);
            f10 = *(const float4*)(nfp1 + m); f11 = *(const float4*)(nfp1 + m + 4);
            STAGE_ND(cur ^ 1, mt + 1)
        }
#pragma unroll
        for (int ct = 0; ct < 8; ct++) {
            int ro = ct * 1024 + rb;
            s16x8 bh = *(const s16x8*)(&lds[cur][ro]);             // EKVT_hi
            s16x8 bl = *(const s16x8*)(&lds[cur][8192 + ro]);      // EKVT_lo
            accN[0][ct] = MFMA16(ah0, bh, accN[0][ct]);
            accN[0][ct] = MFMA16(al0, bh, accN[0][ct]);
            accN[0][ct] = MFMA16(ah0, bl, accN[0][ct]);
            accN[1][ct] = MFMA16(ah1, bh, accN[1][ct]);
            accN[1][ct] = MFMA16(al1, bh, accN[1][ct]);
            accN[1][ct] = MFMA16(ah1, bl, accN[1][ct]);
            bh = *(const s16x8*)(&lds[cur][16384 + ro]);           // EKT_hi
            bl = *(const s16x8*)(&lds[cur][24576 + ro]);           // EKT_lo
            accD[0][ct] = MFMA16(ah0, bh, accD[0][ct]);
            accD[0][ct] = MFMA16(al0, bh, accD[0][ct]);
            accD[0][ct] = MFMA16(ah0, bl, accD[0][ct]);
            accD[1][ct] = MFMA16(ah1, bh, accD[1][ct]);
            accD[1][ct] = MFMA16(al1, bh, accD[1][ct]);
            accD[1][ct] = MFMA16(ah1, bl, accD[1][ct]);
        }
    }
#pragma unroll
    for (int s = 0; s < 2; s++) {
#pragma unroll
        for (int r = 0; r < 4; r++) {
            int n = n0 + s * 16 + kg * 4 + r;
            size_t ro = ((size_t)b * N + n) * D;
#pragma unroll
            for (int ct = 0; ct < 8; ct++) {
                int e = ct * 16 + row;
                float num = accN[s][ct][r], den = accD[s][ct][r];
                float ww = (den != 0.f) ? num / den : 0.f;
                float aafm = SQ[ro + e] * ww;
                unsigned u = __float_as_uint(aafm);
                unsigned hi = u >> 16;
                float fh = __uint_as_float(u & 0xffff0000u);
                unsigned lo = __float_as_uint(aafm - fh) >> 16;
                SQ[ro + e] = __uint_as_float(hi | (lo << 16));
            }
        }
    }
}

// Split enc -> bf16 hi/lo [b][m][128e], SWIZZLED: 8-e chunk c at c ^ (m&7)
__global__ void k_encsplit(const float* __restrict__ enc,
                           unsigned short* __restrict__ Eh, unsigned short* __restrict__ El) {
    size_t i = (size_t)blockIdx.x * 256 + threadIdx.x;   // chunk id
    size_t bm = i >> 4;
    int c = (int)(i & 15);
    int m = (int)(bm & 511);
    int p = c ^ (m & 7);
    const float* src = enc + bm * 128 + c * 8;
    float4 x0 = *(const float4*)(src);
    float4 x1 = *(const float4*)(src + 4);
    s16x8 h, l;
    fsplit8(x0, x1, h, l);
    *(s16x8*)(Eh + bm * 128 + p * 8) = h;
    *(s16x8*)(El + bm * 128 + p * 8) = l;
}

// score = AAFM@enc^T; each wave owns 32 n x 256 m (2 sets) -> B reads amortized 2x.
// dbuf LDS staging, in-loop bias+tanh, fused softmax. Grid 1024 XCD-bijective.
__global__ __launch_bounds__(256, 2) void k_score(
        const float* __restrict__ AAFM,
        const unsigned short* __restrict__ Eh, const unsigned short* __restrict__ El,
        const float* __restrict__ cd, const float* __restrict__ ninf,
        const float* __restrict__ a2p, const float* __restrict__ lsp,
        float* __restrict__ out) {
    int o = blockIdx.x;
    int xcd = o & 7, j = o >> 3;       // j 0..127
    int b = ((j >> 3) << 3) + xcd;     // 16 b's per XCD
    int nb = j & 7;
    int n0 = nb * 64;
    int w = threadIdx.x >> 6, lane = threadIdx.x & 63;
    int row = lane & 15, kg = lane >> 4;
    int ng = w >> 1, mh = w & 1;
    __shared__ __align__(16) char lds[2][32768];  // dbuf x [hi|lo][64 m][256 B]
    __shared__ float redm[64][2];
    __shared__ float reds[64][2];
    float a2ls = a2p[0] * lsp[0];
    const float invs = 0.08838834764831845f;

    // A preload: 2 sets x 16 rows of packed AAFM (hi|lo<<16)
    s16x8 ah[2][4], al[2][4];
#pragma unroll
    for (int s = 0; s < 2; s++) {
        const float* apk = AAFM + ((size_t)b * N + n0 + ng * 32 + s * 16 + row) * D + kg * 8;
#pragma unroll
        for (int es = 0; es < 4; es++) {
            float4 w0 = *(const float4*)(apk + es * 32);
            float4 w1 = *(const float4*)(apk + es * 32 + 4);
            unsigned u;
            u = __float_as_uint(w0.x); ah[s][es][0] = (short)(u & 0xffff); al[s][es][0] = (short)(u >> 16);
            u = __float_as_uint(w0.y); ah[s][es][1] = (short)(u & 0xffff); al[s][es][1] = (short)(u >> 16);
            u = __float_as_uint(w0.z); ah[s][es][2] = (short)(u & 0xffff); al[s][es][2] = (short)(u >> 16);
            u = __float_as_uint(w0.w); ah[s][es][3] = (short)(u & 0xffff); al[s][es][3] = (short)(u >> 16);
            u = __float_as_uint(w1.x); ah[s][es][4] = (short)(u & 0xffff); al[s][es][4] = (short)(u >> 16);
            u = __float_as_uint(w1.y); ah[s][es][5] = (short)(u & 0xffff); al[s][es][5] = (short)(u >> 16);
            u = __float_as_uint(w1.z); ah[s][es][6] = (short)(u & 0xffff); al[s][es][6] = (short)(u >> 16);
            u = __float_as_uint(w1.w); ah[s][es][7] = (short)(u & 0xffff); al[s][es][7] = (short)(u >> 16);
        }
    }
    f32x4 acc[2][16];
#pragma unroll
    for (int s = 0; s < 2; s++)
#pragma unroll
        for (int i = 0; i < 16; i++) acc[s][i] = (f32x4)0.f;

#define STAGE_SC(buf, mc)                                                              \
    _Pragma("unroll")                                                                  \
    for (int jv = 0; jv < 8; jv++) {                                                   \
        int flat = w * 8 + jv;                                                         \
        int arr = flat >> 4, wi = flat & 15;                                           \
        const unsigned short* gb = arr ? El : Eh;                                      \
        const char* src = (const char*)gb                                             \
            + ((size_t)b * M + (mc) * 64 + wi * 4 + kg) * 256 + row * 16;              \
        gload16(src, lds[buf] + arr * 16384 + wi * 1024 + lane * 16);                  \
    }

    STAGE_SC(0, 0)
#pragma unroll
    for (int mc = 0; mc < 8; mc++) {
        int cur = mc & 1;
        __syncthreads();   // drains stages of buf[cur] (issued a full phase ago)
        // MFMA on tile cur (B read once, used by both n-sets)
#pragma unroll
        for (int ct = 0; ct < 2; ct++) {
            int mloc = mh * 32 + ct * 16 + row;
            int a = mc * 2 + ct;
            int rbase = mloc * 256;
            int sw = mloc & 7;
#pragma unroll
            for (int es = 0; es < 4; es++) {
                int ph = (4 * es + kg) ^ sw;
                s16x8 bh = *(const s16x8*)(&lds[cur][rbase + ph * 16]);
                s16x8 bl = *(const s16x8*)(&lds[cur][16384 + rbase + ph * 16]);
                acc[0][a] = MFMA16(ah[0][es], bh, acc[0][a]);
                acc[0][a] = MFMA16(al[0][es], bh, acc[0][a]);
                acc[0][a] = MFMA16(ah[0][es], bl, acc[0][a]);
                acc[1][a] = MFMA16(ah[1][es], bh, acc[1][a]);
                acc[1][a] = MFMA16(al[1][es], bh, acc[1][a]);
                acc[1][a] = MFMA16(ah[1][es], bl, acc[1][a]);
            }
        }
        // issue this tile's cd/ninf loads (both sets)
        float cdv[2][2][4], nfv[2][2][4];
#pragma unroll
        for (int s = 0; s < 2; s++)
#pragma unroll
            for (int ct = 0; ct < 2; ct++)
#pragma unroll
                for (int r = 0; r < 4; r++) {
                    size_t idx = ((size_t)b * N + n0 + ng * 32 + s * 16 + kg * 4 + r) * M
                               + (size_t)mc * 64 + mh * 32 + ct * 16 + row;
                    cdv[s][ct][r] = cd[idx];
                    nfv[s][ct][r] = ninf[idx];
                }
        // stage next tile (completes during tanh + next barrier)
        if (mc < 7) STAGE_SC(cur ^ 1, mc + 1)
        // bias + tanh + mask for this tile
#pragma unroll
        for (int s = 0; s < 2; s++)
#pragma unroll
            for (int ct = 0; ct < 2; ct++) {
                int a = mc * 2 + ct;
#pragma unroll
                for (int r = 0; r < 4; r++) {
                    acc[s][a][r] = 10.f * fast_tanh(fmaf(acc[s][a][r], invs,
                                                         -a2ls * cdv[s][ct][r]))
                                 + nfv[s][ct][r];
                }
            }
    }
    // softmax over m (cross-wave: mh halves share rows)
    float mx[2][4], sm[2][4];
#pragma unroll
    for (int s = 0; s < 2; s++)
#pragma unroll
        for (int r = 0; r < 4; r++) {
            float m = acc[s][0][r];
#pragma unroll
            for (int a = 1; a < 16; a++) m = fmaxf(m, acc[s][a][r]);
#pragma unroll
            for (int sh = 1; sh < 16; sh <<= 1) m = fmaxf(m, __shfl_xor(m, sh, 64));
            mx[s][r] = m;
        }
    if (row == 0) {
#pragma unroll
        for (int s = 0; s < 2; s++)
#pragma unroll
            for (int r = 0; r < 4; r++) redm[ng * 32 + s * 16 + kg * 4 + r][mh] = mx[s][r];
    }
    __syncthreads();
#pragma unroll
    for (int s = 0; s < 2; s++)
#pragma unroll
        for (int r = 0; r < 4; r++) {
            int rl = ng * 32 + s * 16 + kg * 4 + r;
            float m = fmaxf(redm[rl][0], redm[rl][1]);
            float sum = 0.f;
#pragma unroll
            for (int a = 0; a < 16; a++) {
                float e = __expf(acc[s][a][r] - m);
                acc[s][a][r] = e;
                sum += e;
            }
#pragma unroll
            for (int sh = 1; sh < 16; sh <<= 1) sum += __shfl_xor(sum, sh, 64);
            sm[s][r] = sum;
        }
    if (row == 0) {
#pragma unroll
        for (int s = 0; s < 2; s++)
#pragma unroll
            for (int r = 0; r < 4; r++) reds[ng * 32 + s * 16 + kg * 4 + r][mh] = sm[s][r];
    }
    __syncthreads();
#pragma unroll
    for (int s = 0; s < 2; s++) {
#pragma unroll
        for (int r = 0; r < 4; r++) {
            int rl = ng * 32 + s * 16 + kg * 4 + r;
            float inv = 1.f / (reds[rl][0] + reds[rl][1]);
            size_t ro = ((size_t)b * N + n0 + rl) * M;
#pragma unroll
            for (int a = 0; a < 16; a++) {
                size_t mb = (size_t)(a >> 1) * 64 + mh * 32 + (a & 1) * 16 + row;
                out[ro + mb] = acc[s][a][r] * inv;
            }
        }
    }
}

extern "C" void kernel_launch(void* const* d_in, const int* in_sizes, int n_in,
                              void* d_out, int out_size, void* d_ws, size_t ws_size,
                              hipStream_t stream) {
    const float* encl  = (const float*)d_in[0];
    const float* loadv = (const float*)d_in[1];
    const float* cdist = (const float*)d_in[2];
    const float* ls    = (const float*)d_in[3];
    const float* ninf  = (const float*)d_in[4];
    const float* enc   = (const float*)d_in[5];
    const float* Wq    = (const float*)d_in[6];
    const float* Wk    = (const float*)d_in[7];
    const float* Wv    = (const float*)d_in[8];
    const float* a1    = (const float*)d_in[9];
    const float* a2    = (const float*)d_in[10];
    char* ws = (char*)d_ws;
    unsigned short* EKT_hi  = (unsigned short*)(ws);
    unsigned short* EKT_lo  = (unsigned short*)(ws + 16777216);
    unsigned short* EKVT_hi = (unsigned short*)(ws + 33554432);
    unsigned short* EKVT_lo = (unsigned short*)(ws + 50331648);
    float*          SQ      = (float*)(ws + 67108864);
    unsigned short* Wk_hi   = (unsigned short*)(ws + 100663296);
    unsigned short* Wk_lo   = (unsigned short*)(ws + 100663296 + 32768);
    unsigned short* Wv_hi   = (unsigned short*)(ws + 100663296 + 65536);
    unsigned short* Wv_lo   = (unsigned short*)(ws + 100663296 + 98304);
    unsigned short* Wq_hi   = (unsigned short*)(ws + 100663296 + 131072);
    unsigned short* Wq_lo   = (unsigned short*)(ws + 100663296 + 163840);
    unsigned short* ENC_hi  = EKT_hi;   // reuse dead EKT region after k_numden
    unsigned short* ENC_lo  = EKT_lo;
    float* out = (float*)d_out;

    k_prep_w<<<192, 256, 0, stream>>>(Wk, Wv, Wq, Wk_hi, Wk_lo, Wv_hi, Wv_lo, Wq_hi, Wq_lo);
    k_kv<<<dim3(8, 128), 256, 0, stream>>>(enc, Wk_hi, Wk_lo, Wv_hi, Wv_lo,
                                           EKT_hi, EKT_lo, EKVT_hi, EKVT_lo);
    k_q<<<dim3(8, 128), 256, 0, stream>>>(encl, loadv, Wq, Wq_hi, Wq_lo, SQ);
    k_numden<<<512, 256, 0, stream>>>(cdist, ninf, EKVT_hi, EKVT_lo,
                                      EKT_hi, EKT_lo, SQ, a1, ls);
    k_encsplit<<<4096, 256, 0, stream>>>(enc, ENC_hi, ENC_lo);
    k_score<<<1024, 256, 0, stream>>>(SQ, ENC_hi, ENC_lo, cdist, ninf, a2, ls, out);
}